// Round 1
// baseline (2072.226 us; speedup 1.0000x reference)
//
#include <hip/hip_runtime.h>

#define S 2048
#define HID 1024
#define HK 4
#define HV 8
#define DK 128
#define DV 128
#define KEY_DIM 512
#define VAL_DIM 1024
#define CONV_DIM 2048
#define QKVZ_N 3072
#define NEXP 8
#define INTER 512
#define EPS 1e-6f

// ---------------- zero-centered RMSNorm: out = x * rsqrt(mean(x^2)+eps) * (1+w)
__global__ __launch_bounds__(256) void k_rms(const float* __restrict__ x,
                                             const float* __restrict__ w,
                                             float* __restrict__ out) {
  const int row = blockIdx.x;
  const int tid = threadIdx.x;
  const float* xr = x + (size_t)row * HID;
  float4 v = ((const float4*)xr)[tid];
  float ss = v.x*v.x + v.y*v.y + v.z*v.z + v.w*v.w;
  for (int m = 1; m < 64; m <<= 1) ss += __shfl_xor(ss, m);
  __shared__ float sred[4];
  if ((tid & 63) == 0) sred[tid >> 6] = ss;
  __syncthreads();
  float tot = sred[0] + sred[1] + sred[2] + sred[3];
  float scale = 1.0f / sqrtf(tot * (1.0f / HID) + EPS);
  float4 wv = ((const float4*)w)[tid];
  float4 o;
  o.x = v.x * scale * (1.0f + wv.x);
  o.y = v.y * scale * (1.0f + wv.y);
  o.z = v.z * scale * (1.0f + wv.z);
  o.w = v.w * scale * (1.0f + wv.w);
  ((float4*)(out + (size_t)row * HID))[tid] = o;
}

// ---------------- generic f32 GEMM: C = (Cadd?) + A[M,K] @ B[K,N], 64x64 tile
__global__ __launch_bounds__(256) void k_sgemm(const float* __restrict__ A,
                                               const float* __restrict__ B,
                                               const float* __restrict__ Cadd,
                                               float* __restrict__ C,
                                               int M, int N, int K) {
  __shared__ float As[16][68];
  __shared__ float Bs[16][68];
  const int tid = threadIdx.x;
  const int tx = tid & 15, ty = tid >> 4;
  const int m0 = blockIdx.y * 64, n0 = blockIdx.x * 64;
  float acc[4][4] = {};
  const int ar = tid >> 2, ak = (tid & 3) * 4;
  const int br = tid >> 4, bc = (tid & 15) * 4;
  for (int k0 = 0; k0 < K; k0 += 16) {
    float4 av = *(const float4*)&A[(size_t)(m0 + ar) * K + k0 + ak];
    As[ak + 0][ar] = av.x; As[ak + 1][ar] = av.y;
    As[ak + 2][ar] = av.z; As[ak + 3][ar] = av.w;
    *(float4*)&Bs[br][bc] = *(const float4*)&B[(size_t)(k0 + br) * N + n0 + bc];
    __syncthreads();
#pragma unroll
    for (int kk = 0; kk < 16; ++kk) {
      float4 a = *(const float4*)&As[kk][ty * 4];
      float4 b = *(const float4*)&Bs[kk][tx * 4];
      acc[0][0] += a.x * b.x; acc[0][1] += a.x * b.y; acc[0][2] += a.x * b.z; acc[0][3] += a.x * b.w;
      acc[1][0] += a.y * b.x; acc[1][1] += a.y * b.y; acc[1][2] += a.y * b.z; acc[1][3] += a.y * b.w;
      acc[2][0] += a.z * b.x; acc[2][1] += a.z * b.y; acc[2][2] += a.z * b.z; acc[2][3] += a.z * b.w;
      acc[3][0] += a.w * b.x; acc[3][1] += a.w * b.y; acc[3][2] += a.w * b.z; acc[3][3] += a.w * b.w;
    }
    __syncthreads();
  }
#pragma unroll
  for (int i = 0; i < 4; ++i) {
    size_t off = (size_t)(m0 + ty * 4 + i) * N + n0 + tx * 4;
    float4 o;
    o.x = acc[i][0]; o.y = acc[i][1]; o.z = acc[i][2]; o.w = acc[i][3];
    if (Cadd) {
      float4 c = *(const float4*)&Cadd[off];
      o.x += c.x; o.y += c.y; o.z += c.z; o.w += c.w;
    }
    *(float4*)&C[off] = o;
  }
}

// ---------------- ba = x1 @ W_ba  (N=16)
__global__ __launch_bounds__(256) void k_ba(const float* __restrict__ x1,
                                            const float* __restrict__ Wba,
                                            float* __restrict__ ba) {
  const int t = blockIdx.x, tid = threadIdx.x;
  const int n = tid >> 4, kl = tid & 15;
  const float* xr = x1 + (size_t)t * HID;
  float s = 0.f;
  for (int k = kl; k < HID; k += 16) s += xr[k] * Wba[k * 16 + n];
  for (int m = 1; m < 16; m <<= 1) s += __shfl_xor(s, m);
  if (kl == 0) ba[t * 16 + n] = s;
}

// ---------------- beta = sigmoid(b); eg = exp(-exp(A_log)*softplus(a+dt_bias))
__global__ __launch_bounds__(256) void k_bg(const float* __restrict__ ba,
                                            const float* __restrict__ dt_bias,
                                            const float* __restrict__ A_log,
                                            float* __restrict__ eg,
                                            float* __restrict__ beta) {
  int i = blockIdx.x * 256 + threadIdx.x;
  if (i >= S * HV) return;
  int t = i >> 3, h = i & 7;
  float b = ba[t * 16 + h];
  float a = ba[t * 16 + 8 + h];
  beta[i] = 1.f / (1.f + expf(-b));
  float x = a + dt_bias[h];
  float sp = fmaxf(x, 0.f) + log1pf(expf(-fabsf(x)));
  eg[i] = expf(-expf(A_log[h]) * sp);
}

// ---------------- causal depthwise conv (K=4) + silu on qkvz cols [0,2048)
__global__ __launch_bounds__(256) void k_conv(const float* __restrict__ qkvz,
                                              const float* __restrict__ cw,
                                              float* __restrict__ conv) {
  int idx = blockIdx.x * 256 + threadIdx.x;
  int t = idx >> 11, c = idx & 2047;
  float4 w = ((const float4*)cw)[c];
  float acc = 0.f;
  if (t >= 3) {
    acc = qkvz[(size_t)(t - 3) * QKVZ_N + c] * w.x
        + qkvz[(size_t)(t - 2) * QKVZ_N + c] * w.y
        + qkvz[(size_t)(t - 1) * QKVZ_N + c] * w.z
        + qkvz[(size_t)(t    ) * QKVZ_N + c] * w.w;
  } else {
    if (t - 3 >= 0) acc += qkvz[(size_t)(t - 3) * QKVZ_N + c] * w.x;
    if (t - 2 >= 0) acc += qkvz[(size_t)(t - 2) * QKVZ_N + c] * w.y;
    if (t - 1 >= 0) acc += qkvz[(size_t)(t - 1) * QKVZ_N + c] * w.z;
    acc += qkvz[(size_t)t * QKVZ_N + c] * w.w;
  }
  conv[idx] = acc / (1.f + expf(-acc));
}

// ---------------- l2-normalize q,k per source head; repeat to 8 dest heads
__global__ __launch_bounds__(512) void k_prep(const float* __restrict__ conv,
                                              float* __restrict__ qn,
                                              float* __restrict__ kn) {
  const int t = blockIdx.x, tid = threadIdx.x;
  const int sh = tid >> 7;  // source head 0..3
  const int d = tid & 127;
  float qv = conv[(size_t)t * CONV_DIM + sh * DK + d];
  float kv = conv[(size_t)t * CONV_DIM + KEY_DIM + sh * DK + d];
  float sq = qv * qv, sk = kv * kv;
  for (int m = 1; m < 64; m <<= 1) { sq += __shfl_xor(sq, m); sk += __shfl_xor(sk, m); }
  __shared__ float rq[8], rk[8];
  const int wave = tid >> 6;
  if ((tid & 63) == 0) { rq[wave] = sq; rk[wave] = sk; }
  __syncthreads();
  float sumq = rq[sh * 2] + rq[sh * 2 + 1];
  float sumk = rk[sh * 2] + rk[sh * 2 + 1];
  float qs = (1.f / sqrtf(sumq + EPS)) * 0.08838834764831845f;  // * DK^-0.5
  float ks = 1.f / sqrtf(sumk + EPS);
  float qo = qv * qs, ko = kv * ks;
  size_t b0 = (size_t)t * 1024 + (size_t)(sh * 2) * DK + d;
  qn[b0] = qo; qn[b0 + DK] = qo;
  kn[b0] = ko; kn[b0 + DK] = ko;
}

// ---------------- gated delta rule scan. 64 blocks: 8 heads x 8 col-groups.
// 16 cols/block, 16 threads/col, 8 state rows/thread in registers.
__global__ __launch_bounds__(256) void k_scan(const float* __restrict__ qn,
                                              const float* __restrict__ kn,
                                              const float* __restrict__ conv,
                                              const float* __restrict__ eg,
                                              const float* __restrict__ beta,
                                              float* __restrict__ core) {
  const int h = blockIdx.x >> 3;
  const int cg = blockIdx.x & 7;
  const int tid = threadIdx.x;
  const int col = cg * 16 + (tid >> 4);
  const int rg = tid & 15;
  const int r0 = rg * 8;

  float s0 = 0, s1 = 0, s2 = 0, s3 = 0, s4 = 0, s5 = 0, s6 = 0, s7 = 0;

  const float* kb = kn + h * DK + r0;
  const float* qb = qn + h * DK + r0;
  const float* vb = conv + VAL_DIM + h * DV + col;
  const float* egb = eg + h;
  const float* btb = beta + h;
  float* cb = core + h * DV + col;

  float4 ka = *(const float4*)kb;
  float4 kc = *(const float4*)(kb + 4);
  float4 qa = *(const float4*)qb;
  float4 qc = *(const float4*)(qb + 4);
  float vv = vb[0];
  float ge = egb[0];
  float bb = btb[0];

  for (int t = 0; t < S; ++t) {
    const int tn = (t + 1 < S) ? t + 1 : t;
    const size_t toff = (size_t)tn * 1024;
    float4 nka = *(const float4*)(kb + toff);
    float4 nkc = *(const float4*)(kb + toff + 4);
    float4 nqa = *(const float4*)(qb + toff);
    float4 nqc = *(const float4*)(qb + toff + 4);
    float nv = vb[(size_t)tn * CONV_DIM];
    float ng = egb[(size_t)tn * HV];
    float nb = btb[(size_t)tn * HV];

    s0 *= ge; s1 *= ge; s2 *= ge; s3 *= ge;
    s4 *= ge; s5 *= ge; s6 *= ge; s7 *= ge;
    float kv = ((s0 * ka.x + s1 * ka.y) + (s2 * ka.z + s3 * ka.w))
             + ((s4 * kc.x + s5 * kc.y) + (s6 * kc.z + s7 * kc.w));
    kv += __shfl_xor(kv, 1);
    kv += __shfl_xor(kv, 2);
    kv += __shfl_xor(kv, 4);
    kv += __shfl_xor(kv, 8);
    const float delta = (vv - kv) * bb;
    s0 += ka.x * delta; s1 += ka.y * delta; s2 += ka.z * delta; s3 += ka.w * delta;
    s4 += kc.x * delta; s5 += kc.y * delta; s6 += kc.z * delta; s7 += kc.w * delta;
    float o = ((s0 * qa.x + s1 * qa.y) + (s2 * qa.z + s3 * qa.w))
            + ((s4 * qc.x + s5 * qc.y) + (s6 * qc.z + s7 * qc.w));
    o += __shfl_xor(o, 1);
    o += __shfl_xor(o, 2);
    o += __shfl_xor(o, 4);
    o += __shfl_xor(o, 8);
    if (rg == 0) cb[(size_t)t * 1024] = o;

    ka = nka; kc = nkc; qa = nqa; qc = nqc; vv = nv; ge = ng; bb = nb;
  }
}

// ---------------- gated RMSNorm per value head * silu(z); in-place safe
__global__ __launch_bounds__(256) void k_gatenorm(const float* __restrict__ core,
                                                  const float* __restrict__ qkvz,
                                                  const float* __restrict__ gnw,
                                                  float* __restrict__ y) {
  const int t = blockIdx.x, tid = threadIdx.x;
  const int wave = tid >> 6, lane = tid & 63;
  const int h = blockIdx.y * 4 + wave;
  const float* cbp = core + (size_t)t * 1024 + h * DV;
  float c0 = cbp[lane], c1 = cbp[lane + 64];
  float ss = c0 * c0 + c1 * c1;
  for (int m = 1; m < 64; m <<= 1) ss += __shfl_xor(ss, m);
  float scale = 1.f / sqrtf(ss * (1.0f / DV) + EPS);
  const float* zb = qkvz + (size_t)t * QKVZ_N + 2 * KEY_DIM + VAL_DIM + h * DV;
  float z0 = zb[lane], z1 = zb[lane + 64];
  float g0 = gnw[lane], g1 = gnw[lane + 64];
  float o0 = c0 * scale * g0 * (z0 / (1.f + expf(-z0)));
  float o1 = c1 * scale * g1 * (z1 / (1.f + expf(-z1)));
  float* yb = y + (size_t)t * 1024 + h * DV;
  yb[lane] = o0; yb[lane + 64] = o1;
}

// ---------------- router: logits, softmax-top2, write weights + counts + topi
__global__ __launch_bounds__(256) void k_router(const float* __restrict__ x2,
                                                const float* __restrict__ Wr,
                                                float* __restrict__ rinfo,
                                                int* __restrict__ cnt,
                                                float* __restrict__ outTopi) {
  const int t = blockIdx.x, tid = threadIdx.x;
  const int n = tid >> 5, kl = tid & 31;
  const float* xr = x2 + (size_t)t * HID;
  float s = 0.f;
  for (int k = kl; k < HID; k += 32) s += xr[k] * Wr[k * 8 + n];
  for (int m = 1; m < 32; m <<= 1) s += __shfl_xor(s, m);
  __shared__ float lg[8];
  if (kl == 0) lg[n] = s;
  __syncthreads();
  if (tid == 0) {
    int i0 = 0; float m0 = lg[0];
    for (int e = 1; e < 8; ++e) if (lg[e] > m0) { m0 = lg[e]; i0 = e; }
    int i1 = -1; float m1 = -1e30f;
    for (int e = 0; e < 8; ++e) if (e != i0 && lg[e] > m1) { m1 = lg[e]; i1 = e; }
    float e1 = expf(m1 - m0);
    float w0 = 1.f / (1.f + e1);
    float w1 = e1 / (1.f + e1);
    rinfo[t * 4 + 0] = (float)i0; rinfo[t * 4 + 1] = (float)i1;
    rinfo[t * 4 + 2] = w0;        rinfo[t * 4 + 3] = w1;
    atomicAdd(&cnt[i0], 1);
    atomicAdd(&cnt[i1], 1);
    outTopi[t * 2 + 0] = (float)i0;
    outTopi[t * 2 + 1] = (float)i1;
  }
}

__global__ void k_offsets(const int* __restrict__ cnt, int* __restrict__ offs,
                          int* __restrict__ cnt2) {
  if (threadIdx.x == 0) {
    int a = 0;
    for (int e = 0; e < 8; ++e) { offs[e] = a; a += cnt[e]; cnt2[e] = 0; }
  }
}

__global__ __launch_bounds__(256) void k_scatter(const float* __restrict__ rinfo,
                                                 const int* __restrict__ offs,
                                                 int* __restrict__ cnt2,
                                                 int* __restrict__ pairTok,
                                                 float* __restrict__ pairW) {
  int t = blockIdx.x * 256 + threadIdx.x;
  if (t >= S) return;
  int i0 = (int)rinfo[t * 4 + 0], i1 = (int)rinfo[t * 4 + 1];
  float w0 = rinfo[t * 4 + 2], w1 = rinfo[t * 4 + 3];
  int p0 = offs[i0] + atomicAdd(&cnt2[i0], 1);
  pairTok[p0] = t; pairW[p0] = w0;
  int p1 = offs[i1] + atomicAdd(&cnt2[i1], 1);
  pairTok[p1] = t; pairW[p1] = w1;
}

// ---------------- MoE stage 1: act = silu(Xg) * Xu, gathered rows per expert
__global__ __launch_bounds__(256) void k_moe1(const float* __restrict__ x2,
                                              const float* __restrict__ Wg,
                                              const float* __restrict__ Wu,
                                              const int* __restrict__ offs,
                                              const int* __restrict__ cnt,
                                              const int* __restrict__ pairTok,
                                              float* __restrict__ act) {
  const int e = blockIdx.z;
  const int count = cnt[e];
  const int m0 = blockIdx.y * 64;
  if (m0 >= count) return;
  const int n0 = blockIdx.x * 64;
  const int base = offs[e];
  __shared__ float As[16][68], Bg[16][68], Bu[16][68];
  __shared__ int toks[64];
  const int tid = threadIdx.x;
  if (tid < 64) toks[tid] = (m0 + tid < count) ? pairTok[base + m0 + tid] : 0;
  __syncthreads();
  const float* WgB = Wg + (size_t)e * HID * INTER;
  const float* WuB = Wu + (size_t)e * HID * INTER;
  float accg[4][4] = {}, accu[4][4] = {};
  const int tx = tid & 15, ty = tid >> 4;
  const int ar = tid >> 2, ak = (tid & 3) * 4;
  const int br = tid >> 4, bc = (tid & 15) * 4;
  const bool va = (m0 + ar) < count;
  for (int k0 = 0; k0 < HID; k0 += 16) {
    float4 av = va ? *(const float4*)&x2[(size_t)toks[ar] * HID + k0 + ak]
                   : make_float4(0.f, 0.f, 0.f, 0.f);
    As[ak + 0][ar] = av.x; As[ak + 1][ar] = av.y;
    As[ak + 2][ar] = av.z; As[ak + 3][ar] = av.w;
    *(float4*)&Bg[br][bc] = *(const float4*)&WgB[(size_t)(k0 + br) * INTER + n0 + bc];
    *(float4*)&Bu[br][bc] = *(const float4*)&WuB[(size_t)(k0 + br) * INTER + n0 + bc];
    __syncthreads();
#pragma unroll
    for (int kk = 0; kk < 16; ++kk) {
      float4 a = *(const float4*)&As[kk][ty * 4];
      float4 g = *(const float4*)&Bg[kk][tx * 4];
      float4 u = *(const float4*)&Bu[kk][tx * 4];
      accg[0][0] += a.x * g.x; accg[0][1] += a.x * g.y; accg[0][2] += a.x * g.z; accg[0][3] += a.x * g.w;
      accg[1][0] += a.y * g.x; accg[1][1] += a.y * g.y; accg[1][2] += a.y * g.z; accg[1][3] += a.y * g.w;
      accg[2][0] += a.z * g.x; accg[2][1] += a.z * g.y; accg[2][2] += a.z * g.z; accg[2][3] += a.z * g.w;
      accg[3][0] += a.w * g.x; accg[3][1] += a.w * g.y; accg[3][2] += a.w * g.z; accg[3][3] += a.w * g.w;
      accu[0][0] += a.x * u.x; accu[0][1] += a.x * u.y; accu[0][2] += a.x * u.z; accu[0][3] += a.x * u.w;
      accu[1][0] += a.y * u.x; accu[1][1] += a.y * u.y; accu[1][2] += a.y * u.z; accu[1][3] += a.y * u.w;
      accu[2][0] += a.z * u.x; accu[2][1] += a.z * u.y; accu[2][2] += a.z * u.z; accu[2][3] += a.z * u.w;
      accu[3][0] += a.w * u.x; accu[3][1] += a.w * u.y; accu[3][2] += a.w * u.z; accu[3][3] += a.w * u.w;
    }
    __syncthreads();
  }
#pragma unroll
  for (int i = 0; i < 4; ++i) {
    int r = ty * 4 + i;
    if (m0 + r < count) {
#pragma unroll
      for (int j = 0; j < 4; ++j) {
        float gv = accg[i][j], uv = accu[i][j];
        act[(size_t)(base + m0 + r) * INTER + n0 + tx * 4 + j] =
            gv / (1.f + expf(-gv)) * uv;
      }
    }
  }
}

// ---------------- MoE stage 2: out += w * (act @ W_down[e]) scattered by token
__global__ __launch_bounds__(256) void k_moe2(const float* __restrict__ act,
                                              const float* __restrict__ Wd,
                                              const int* __restrict__ offs,
                                              const int* __restrict__ cnt,
                                              const int* __restrict__ pairTok,
                                              const float* __restrict__ pairW,
                                              float* __restrict__ out) {
  const int e = blockIdx.z;
  const int count = cnt[e];
  const int m0 = blockIdx.y * 64;
  if (m0 >= count) return;
  const int n0 = blockIdx.x * 64;
  const int base = offs[e];
  __shared__ float As[16][68], Bs[16][68];
  const int tid = threadIdx.x;
  const int tx = tid & 15, ty = tid >> 4;
  const int ar = tid >> 2, ak = (tid & 3) * 4;
  const int br = tid >> 4, bc = (tid & 15) * 4;
  const bool va = (m0 + ar) < count;
  const float* WdB = Wd + (size_t)e * INTER * HID;
  float acc[4][4] = {};
  for (int k0 = 0; k0 < INTER; k0 += 16) {
    float4 av = va ? *(const float4*)&act[(size_t)(base + m0 + ar) * INTER + k0 + ak]
                   : make_float4(0.f, 0.f, 0.f, 0.f);
    As[ak + 0][ar] = av.x; As[ak + 1][ar] = av.y;
    As[ak + 2][ar] = av.z; As[ak + 3][ar] = av.w;
    *(float4*)&Bs[br][bc] = *(const float4*)&WdB[(size_t)(k0 + br) * HID + n0 + bc];
    __syncthreads();
#pragma unroll
    for (int kk = 0; kk < 16; ++kk) {
      float4 a = *(const float4*)&As[kk][ty * 4];
      float4 b = *(const float4*)&Bs[kk][tx * 4];
      acc[0][0] += a.x * b.x; acc[0][1] += a.x * b.y; acc[0][2] += a.x * b.z; acc[0][3] += a.x * b.w;
      acc[1][0] += a.y * b.x; acc[1][1] += a.y * b.y; acc[1][2] += a.y * b.z; acc[1][3] += a.y * b.w;
      acc[2][0] += a.z * b.x; acc[2][1] += a.z * b.y; acc[2][2] += a.z * b.z; acc[2][3] += a.z * b.w;
      acc[3][0] += a.w * b.x; acc[3][1] += a.w * b.y; acc[3][2] += a.w * b.z; acc[3][3] += a.w * b.w;
    }
    __syncthreads();
  }
#pragma unroll
  for (int i = 0; i < 4; ++i) {
    int r = ty * 4 + i;
    if (m0 + r < count) {
      int tok = pairTok[base + m0 + r];
      float w = pairW[base + m0 + r];
#pragma unroll
      for (int j = 0; j < 4; ++j)
        atomicAdd(&out[(size_t)tok * HID + n0 + tx * 4 + j], acc[i][j] * w);
    }
  }
}

extern "C" void kernel_launch(void* const* d_in, const int* in_sizes, int n_in,
                              void* d_out, int out_size, void* d_ws, size_t ws_size,
                              hipStream_t stream) {
  const float* hid      = (const float*)d_in[0];
  const float* w_ln1    = (const float*)d_in[1];
  const float* w_ln2    = (const float*)d_in[2];
  const float* W_qkvz   = (const float*)d_in[3];
  const float* W_ba     = (const float*)d_in[4];
  const float* conv_w   = (const float*)d_in[5];
  const float* dt_bias  = (const float*)d_in[6];
  const float* A_log    = (const float*)d_in[7];
  const float* gnw      = (const float*)d_in[8];
  const float* W_out    = (const float*)d_in[9];
  const float* W_router = (const float*)d_in[10];
  const float* W_gate   = (const float*)d_in[11];
  const float* W_up     = (const float*)d_in[12];
  const float* W_down   = (const float*)d_in[13];

  float* ws = (float*)d_ws;
  const size_t N1 = (size_t)S * HID;
  float* x1    = ws;                       // also x2 (reused after qkvz+ba)
  float* qkvz  = x1 + N1;                  // 2048*3072
  float* conv  = qkvz + (size_t)S * QKVZ_N;// 2048*2048, reused as act later
  float* qn    = conv + (size_t)S * CONV_DIM;
  float* kn    = qn + N1;
  float* core  = kn + N1;                  // also y (gatenorm is in-place safe)
  float* hbuf  = core + N1;
  float* ba    = hbuf + N1;                // 2048*16
  float* egb   = ba + (size_t)S * 16;      // 2048*8
  float* betab = egb + (size_t)S * HV;     // 2048*8
  float* rinfo = betab + (size_t)S * HV;   // 2048*4
  float* pairW = rinfo + (size_t)S * 4;    // 4096
  int*   ints  = (int*)(pairW + 4096);
  int* cnt = ints;          // 8
  int* cnt2 = ints + 8;     // 8
  int* offs = ints + 16;    // 8
  int* pairTok = ints + 32; // 4096
  float* x2 = x1;
  float* act = conv;
  float* y = core;

  float* outF = (float*)d_out;

  hipMemsetAsync(cnt, 0, 16 * sizeof(int), stream);

  k_rms<<<S, 256, 0, stream>>>(hid, w_ln1, x1);
  k_sgemm<<<dim3(QKVZ_N / 64, S / 64), 256, 0, stream>>>(x1, W_qkvz, nullptr, qkvz,
                                                         S, QKVZ_N, HID);
  k_ba<<<S, 256, 0, stream>>>(x1, W_ba, ba);
  k_bg<<<(S * HV + 255) / 256, 256, 0, stream>>>(ba, dt_bias, A_log, egb, betab);
  k_conv<<<(S * CONV_DIM) / 256, 256, 0, stream>>>(qkvz, conv_w, conv);
  k_prep<<<S, 512, 0, stream>>>(conv, qn, kn);
  k_scan<<<64, 256, 0, stream>>>(qn, kn, conv, egb, betab, core);
  k_gatenorm<<<dim3(S, 2), 256, 0, stream>>>(core, qkvz, gnw, y);
  k_sgemm<<<dim3(HID / 64, S / 64), 256, 0, stream>>>(y, W_out, hid, hbuf,
                                                      S, HID, VAL_DIM);
  k_rms<<<S, 256, 0, stream>>>(hbuf, w_ln2, x2);
  k_router<<<S, 256, 0, stream>>>(x2, W_router, rinfo, cnt, outF + N1);
  k_offsets<<<1, 64, 0, stream>>>(cnt, offs, cnt2);
  k_scatter<<<(S + 255) / 256, 256, 0, stream>>>(rinfo, offs, cnt2, pairTok, pairW);
  k_moe1<<<dim3(INTER / 64, S / 64, NEXP), 256, 0, stream>>>(x2, W_gate, W_up, offs,
                                                             cnt, pairTok, act);
  hipMemcpyAsync(d_out, hbuf, N1 * sizeof(float), hipMemcpyDeviceToDevice, stream);
  k_moe2<<<dim3(HID / 64, S / 64, NEXP), 256, 0, stream>>>(act, W_down, offs, cnt,
                                                           pairTok, pairW, outF);
}

// Round 4
// 1404.739 us; speedup vs baseline: 1.4752x; 1.4752x over previous
//
#include <hip/hip_runtime.h>

#define S 2048
#define HID 1024
#define HK 4
#define HV 8
#define DK 128
#define DV 128
#define KEY_DIM 512
#define VAL_DIM 1024
#define CONV_DIM 2048
#define QKVZ_N 3072
#define NEXP 8
#define INTER 512
#define EPS 1e-6f
#define CK 64
#define NC 32

// ---------------- zero-centered RMSNorm: out = x * rsqrt(mean(x^2)+eps) * (1+w)
__global__ __launch_bounds__(256) void k_rms(const float* __restrict__ x,
                                             const float* __restrict__ w,
                                             float* __restrict__ out) {
  const int row = blockIdx.x;
  const int tid = threadIdx.x;
  const float* xr = x + (size_t)row * HID;
  float4 v = ((const float4*)xr)[tid];
  float ss = v.x*v.x + v.y*v.y + v.z*v.z + v.w*v.w;
  for (int m = 1; m < 64; m <<= 1) ss += __shfl_xor(ss, m);
  __shared__ float sred[4];
  if ((tid & 63) == 0) sred[tid >> 6] = ss;
  __syncthreads();
  float tot = sred[0] + sred[1] + sred[2] + sred[3];
  float scale = 1.0f / sqrtf(tot * (1.0f / HID) + EPS);
  float4 wv = ((const float4*)w)[tid];
  float4 o;
  o.x = v.x * scale * (1.0f + wv.x);
  o.y = v.y * scale * (1.0f + wv.y);
  o.z = v.z * scale * (1.0f + wv.z);
  o.w = v.w * scale * (1.0f + wv.w);
  ((float4*)(out + (size_t)row * HID))[tid] = o;
}

// ---------------- generic f32 GEMM: C = (Cadd?) + A[M,K] @ B[K,N], 64x64 tile
__global__ __launch_bounds__(256) void k_sgemm(const float* __restrict__ A,
                                               const float* __restrict__ B,
                                               const float* __restrict__ Cadd,
                                               float* __restrict__ C,
                                               int M, int N, int K) {
  __shared__ float As[16][68];
  __shared__ float Bs[16][68];
  const int tid = threadIdx.x;
  const int tx = tid & 15, ty = tid >> 4;
  const int m0 = blockIdx.y * 64, n0 = blockIdx.x * 64;
  float acc[4][4] = {};
  const int ar = tid >> 2, ak = (tid & 3) * 4;
  const int br = tid >> 4, bc = (tid & 15) * 4;
  for (int k0 = 0; k0 < K; k0 += 16) {
    float4 av = *(const float4*)&A[(size_t)(m0 + ar) * K + k0 + ak];
    As[ak + 0][ar] = av.x; As[ak + 1][ar] = av.y;
    As[ak + 2][ar] = av.z; As[ak + 3][ar] = av.w;
    *(float4*)&Bs[br][bc] = *(const float4*)&B[(size_t)(k0 + br) * N + n0 + bc];
    __syncthreads();
#pragma unroll
    for (int kk = 0; kk < 16; ++kk) {
      float4 a = *(const float4*)&As[kk][ty * 4];
      float4 b = *(const float4*)&Bs[kk][tx * 4];
      acc[0][0] += a.x * b.x; acc[0][1] += a.x * b.y; acc[0][2] += a.x * b.z; acc[0][3] += a.x * b.w;
      acc[1][0] += a.y * b.x; acc[1][1] += a.y * b.y; acc[1][2] += a.y * b.z; acc[1][3] += a.y * b.w;
      acc[2][0] += a.z * b.x; acc[2][1] += a.z * b.y; acc[2][2] += a.z * b.z; acc[2][3] += a.z * b.w;
      acc[3][0] += a.w * b.x; acc[3][1] += a.w * b.y; acc[3][2] += a.w * b.z; acc[3][3] += a.w * b.w;
    }
    __syncthreads();
  }
#pragma unroll
  for (int i = 0; i < 4; ++i) {
    size_t off = (size_t)(m0 + ty * 4 + i) * N + n0 + tx * 4;
    float4 o;
    o.x = acc[i][0]; o.y = acc[i][1]; o.z = acc[i][2]; o.w = acc[i][3];
    if (Cadd) {
      float4 c = *(const float4*)&Cadd[off];
      o.x += c.x; o.y += c.y; o.z += c.z; o.w += c.w;
    }
    *(float4*)&C[off] = o;
  }
}

// ---------------- ba = x1 @ W_ba  (N=16)
__global__ __launch_bounds__(256) void k_ba(const float* __restrict__ x1,
                                            const float* __restrict__ Wba,
                                            float* __restrict__ ba) {
  const int t = blockIdx.x, tid = threadIdx.x;
  const int n = tid >> 4, kl = tid & 15;
  const float* xr = x1 + (size_t)t * HID;
  float s = 0.f;
  for (int k = kl; k < HID; k += 16) s += xr[k] * Wba[k * 16 + n];
  for (int m = 1; m < 16; m <<= 1) s += __shfl_xor(s, m);
  if (kl == 0) ba[t * 16 + n] = s;
}

// ---------------- beta = sigmoid(b); g = -exp(A_log)*softplus(a+dt_bias)
__global__ __launch_bounds__(256) void k_bg(const float* __restrict__ ba,
                                            const float* __restrict__ dt_bias,
                                            const float* __restrict__ A_log,
                                            float* __restrict__ gb,
                                            float* __restrict__ beta) {
  int i = blockIdx.x * 256 + threadIdx.x;
  if (i >= S * HV) return;
  int t = i >> 3, h = i & 7;
  float b = ba[t * 16 + h];
  float a = ba[t * 16 + 8 + h];
  beta[i] = 1.f / (1.f + expf(-b));
  float x = a + dt_bias[h];
  float sp = fmaxf(x, 0.f) + log1pf(expf(-fabsf(x)));
  gb[i] = -expf(A_log[h]) * sp;
}

// ---------------- causal depthwise conv (K=4) + silu on qkvz cols [0,2048)
__global__ __launch_bounds__(256) void k_conv(const float* __restrict__ qkvz,
                                              const float* __restrict__ cw,
                                              float* __restrict__ conv) {
  int idx = blockIdx.x * 256 + threadIdx.x;
  int t = idx >> 11, c = idx & 2047;
  float4 w = ((const float4*)cw)[c];
  float acc = 0.f;
  if (t >= 3) {
    acc = qkvz[(size_t)(t - 3) * QKVZ_N + c] * w.x
        + qkvz[(size_t)(t - 2) * QKVZ_N + c] * w.y
        + qkvz[(size_t)(t - 1) * QKVZ_N + c] * w.z
        + qkvz[(size_t)(t    ) * QKVZ_N + c] * w.w;
  } else {
    if (t - 3 >= 0) acc += qkvz[(size_t)(t - 3) * QKVZ_N + c] * w.x;
    if (t - 2 >= 0) acc += qkvz[(size_t)(t - 2) * QKVZ_N + c] * w.y;
    if (t - 1 >= 0) acc += qkvz[(size_t)(t - 1) * QKVZ_N + c] * w.z;
    acc += qkvz[(size_t)t * QKVZ_N + c] * w.w;
  }
  conv[idx] = acc / (1.f + expf(-acc));
}

// ---------------- l2-normalize q,k per source head; repeat to 8 dest heads
__global__ __launch_bounds__(512) void k_prep(const float* __restrict__ conv,
                                              float* __restrict__ qn,
                                              float* __restrict__ kn) {
  const int t = blockIdx.x, tid = threadIdx.x;
  const int sh = tid >> 7;  // source head 0..3
  const int d = tid & 127;
  float qv = conv[(size_t)t * CONV_DIM + sh * DK + d];
  float kv = conv[(size_t)t * CONV_DIM + KEY_DIM + sh * DK + d];
  float sq = qv * qv, sk = kv * kv;
  for (int m = 1; m < 64; m <<= 1) { sq += __shfl_xor(sq, m); sk += __shfl_xor(sk, m); }
  __shared__ float rq[8], rk[8];
  const int wave = tid >> 6;
  if ((tid & 63) == 0) { rq[wave] = sq; rk[wave] = sk; }
  __syncthreads();
  float sumq = rq[sh * 2] + rq[sh * 2 + 1];
  float sumk = rk[sh * 2] + rk[sh * 2 + 1];
  float qs = (1.f / sqrtf(sumq + EPS)) * 0.08838834764831845f;  // * DK^-0.5
  float ks = 1.f / sqrtf(sumk + EPS);
  float qo = qv * qs, ko = kv * ks;
  size_t b0 = (size_t)t * 1024 + (size_t)(sh * 2) * DK + d;
  qn[b0] = qo; qn[b0 + DK] = qo;
  kn[b0] = ko; kn[b0 + DK] = ko;
}

// ================= chunked gated delta rule =================
// Phase A: per (head, chunk): decay cumsum, M=(I+mask(beta e^{ct-cj} k.k))^-1 etc.
__global__ __launch_bounds__(256) void k_chunkA(
    const float* __restrict__ qn, const float* __restrict__ kn,
    const float* __restrict__ conv, const float* __restrict__ gbuf,
    const float* __restrict__ betab,
    float* __restrict__ Upre, float* __restrict__ WpT,
    float* __restrict__ Qdt, float* __restrict__ Kdm,
    float* __restrict__ BqT, float* __restrict__ dec) {
  const int h = blockIdx.x >> 5;
  const int ch = blockIdx.x & 31;
  const int tid = threadIdx.x;
  const int t_base = ch * CK;

  __shared__ float KT[128][68];
  __shared__ float UB[8704];          // union: Vsm [64][132] / QT [128][68]
  __shared__ float Am[64][68];
  __shared__ float Mm[64][68];
  __shared__ float c_l[64], b_l[64], sW[64], seQ[64], sKd[64];

  // ---- load K^T (transposed into LDS) ----
#pragma unroll
  for (int i = 0; i < 8; ++i) {
    int w = (i * 256 + tid) * 4;
    int tt = w >> 7, r = w & 127;
    float4 v = *(const float4*)&kn[(size_t)(t_base + tt) * 1024 + h * 128 + r];
    KT[r + 0][tt] = v.x; KT[r + 1][tt] = v.y; KT[r + 2][tt] = v.z; KT[r + 3][tt] = v.w;
  }
  if (tid < 64) {
    c_l[tid] = gbuf[(t_base + tid) * HV + h];
    b_l[tid] = betab[(t_base + tid) * HV + h];
  }
  __syncthreads();
  if (tid == 0) {
    float run = 0.f;
    for (int t = 0; t < 64; ++t) { run += c_l[t]; c_l[t] = run; }
    dec[h * NC + ch] = expf(run);
  }
  __syncthreads();
  if (tid < 64) {
    sW[tid] = b_l[tid] * expf(c_l[tid]);
    seQ[tid] = expf(c_l[tid]);
    sKd[tid] = expf(c_l[63] - c_l[tid]);
  }
  __syncthreads();

  // ---- A[t][j] = beta_t e^{ct-cj} (k_t.k_j), j<t ----
  {
    const int t0 = (tid >> 4) * 4, j0 = (tid & 15) * 4;
    float acc[4][4] = {};
    for (int r = 0; r < 128; ++r) {
      float4 a = *(const float4*)&KT[r][t0];
      float4 b = *(const float4*)&KT[r][j0];
      float av[4] = {a.x, a.y, a.z, a.w};
      float bv[4] = {b.x, b.y, b.z, b.w};
#pragma unroll
      for (int i = 0; i < 4; ++i)
#pragma unroll
        for (int j = 0; j < 4; ++j) acc[i][j] += av[i] * bv[j];
    }
#pragma unroll
    for (int i = 0; i < 4; ++i)
#pragma unroll
      for (int j = 0; j < 4; ++j) {
        int t = t0 + i, jj = j0 + j;
        Am[t][jj] = (jj < t) ? b_l[t] * expf(c_l[t] - c_l[jj]) * acc[i][j] : 0.f;
      }
  }
  __syncthreads();

  // ---- M = (I+A)^{-1}, forward substitution: thread c owns column c ----
  if (tid < 64) {
    const int c = tid;
    Mm[0][c] = (c == 0) ? 1.f : 0.f;
    for (int t = 1; t < 64; ++t) {
      float a = (c == t) ? 1.f : 0.f;
      for (int j = 0; j < t; ++j) a -= Am[t][j] * Mm[j][c];
      Mm[t][c] = a;
    }
  }
  __syncthreads();

  // ---- stage V*beta ----
  float* Vsm = UB;  // [64][132]
#pragma unroll
  for (int i = 0; i < 8; ++i) {
    int w = (i * 256 + tid) * 4;
    int j = w >> 7, cc = w & 127;
    float4 v = *(const float4*)&conv[(size_t)(t_base + j) * CONV_DIM + 1024 + h * 128 + cc];
    float bj = b_l[j];
    v.x *= bj; v.y *= bj; v.z *= bj; v.w *= bj;
    *(float4*)&Vsm[j * 132 + cc] = v;
  }
  __syncthreads();

  const size_t cb = (size_t)h * NC + ch;
  // ---- Upre = M @ (beta V): 64x128, tile 4t x 8c ----
  {
    const int t0 = (tid >> 4) * 4, c0 = (tid & 15) * 8;
    float acc[4][8] = {};
    for (int j = 0; j < 64; ++j) {
      float m[4];
#pragma unroll
      for (int i = 0; i < 4; ++i) m[i] = Mm[t0 + i][j];
      float4 va = *(const float4*)&Vsm[j * 132 + c0];
      float4 vb = *(const float4*)&Vsm[j * 132 + c0 + 4];
      float v[8] = {va.x, va.y, va.z, va.w, vb.x, vb.y, vb.z, vb.w};
#pragma unroll
      for (int i = 0; i < 4; ++i)
#pragma unroll
        for (int c = 0; c < 8; ++c) acc[i][c] += m[i] * v[c];
    }
#pragma unroll
    for (int i = 0; i < 4; ++i) {
      float4 o0 = {acc[i][0], acc[i][1], acc[i][2], acc[i][3]};
      float4 o1 = {acc[i][4], acc[i][5], acc[i][6], acc[i][7]};
      *(float4*)&Upre[cb * 8192 + (size_t)(t0 + i) * 128 + c0] = o0;
      *(float4*)&Upre[cb * 8192 + (size_t)(t0 + i) * 128 + c0 + 4] = o1;
    }
  }
  // ---- WpT[r][t] = sum_j KT[r][j]*sW[j]*Mm[t][j], tile 4r x 8t ----
  {
    const int r0 = (tid >> 3) * 4, t0 = (tid & 7) * 8;
    float acc[4][8] = {};
    for (int j = 0; j < 64; ++j) {
      float s = sW[j];
      float kk[4];
#pragma unroll
      for (int i = 0; i < 4; ++i) kk[i] = KT[r0 + i][j] * s;
      float m[8];
#pragma unroll
      for (int t = 0; t < 8; ++t) m[t] = Mm[t0 + t][j];
#pragma unroll
      for (int i = 0; i < 4; ++i)
#pragma unroll
        for (int t = 0; t < 8; ++t) acc[i][t] += kk[i] * m[t];
    }
#pragma unroll
    for (int i = 0; i < 4; ++i) {
      float4 o0 = {acc[i][0], acc[i][1], acc[i][2], acc[i][3]};
      float4 o1 = {acc[i][4], acc[i][5], acc[i][6], acc[i][7]};
      *(float4*)&WpT[cb * 8192 + (size_t)(r0 + i) * 64 + t0] = o0;
      *(float4*)&WpT[cb * 8192 + (size_t)(r0 + i) * 64 + t0 + 4] = o1;
    }
  }
  __syncthreads();  // before overwriting UB with QT

  // ---- stage Q^T ----
  float* QT = UB;  // [128][68]
#pragma unroll
  for (int i = 0; i < 8; ++i) {
    int w = (i * 256 + tid) * 4;
    int tt = w >> 7, r = w & 127;
    float4 v = *(const float4*)&qn[(size_t)(t_base + tt) * 1024 + h * 128 + r];
    QT[(r + 0) * 68 + tt] = v.x; QT[(r + 1) * 68 + tt] = v.y;
    QT[(r + 2) * 68 + tt] = v.z; QT[(r + 3) * 68 + tt] = v.w;
  }
  __syncthreads();

  // ---- BqT[j][t] = (j<=t) e^{ct-cj} (q_t.k_j) ----
  {
    const int t0 = (tid >> 4) * 4, j0 = (tid & 15) * 4;
    float acc[4][4] = {};
    for (int r = 0; r < 128; ++r) {
      float4 a = *(const float4*)&QT[r * 68 + t0];
      float4 b = *(const float4*)&KT[r][j0];
      float av[4] = {a.x, a.y, a.z, a.w};
      float bv[4] = {b.x, b.y, b.z, b.w};
#pragma unroll
      for (int i = 0; i < 4; ++i)
#pragma unroll
        for (int j = 0; j < 4; ++j) acc[i][j] += av[i] * bv[j];
    }
#pragma unroll
    for (int i = 0; i < 4; ++i)
#pragma unroll
      for (int j = 0; j < 4; ++j) {
        int t = t0 + i, jj = j0 + j;
        BqT[cb * 4096 + (size_t)jj * 64 + t] =
            (jj <= t) ? expf(c_l[t] - c_l[jj]) * acc[i][j] : 0.f;
      }
  }
  // ---- Qdt[r][t] = QT[r][t]*e^{ct}  (layout [128][64]) ----
#pragma unroll
  for (int i = 0; i < 8; ++i) {
    int w = (i * 256 + tid) * 4;
    int r = w >> 6, t = w & 63;
    float4 q = *(const float4*)&QT[r * 68 + t];
    float4 s = *(const float4*)&seQ[t];
    q.x *= s.x; q.y *= s.y; q.z *= s.z; q.w *= s.w;
    *(float4*)&Qdt[cb * 8192 + w] = q;
  }
  // ---- Kd[t][r] = KT[r][t]*e^{cC-ct}  (layout [64][128]) ----
#pragma unroll
  for (int i = 0; i < 8; ++i) {
    int w = (i * 256 + tid) * 4;
    int t = w >> 7, r = w & 127;
    float s = sKd[t];
    float4 o;
    o.x = KT[r + 0][t] * s; o.y = KT[r + 1][t] * s;
    o.z = KT[r + 2][t] * s; o.w = KT[r + 3][t] * s;
    *(float4*)&Kdm[cb * 8192 + w] = o;
  }
}

// Phase B: sequential over chunks. 32 blocks = 8 heads x 4 col-groups (32 cols).
__global__ __launch_bounds__(256) void k_chunkB(
    const float* __restrict__ Upre, const float* __restrict__ WpT,
    const float* __restrict__ Qdt, const float* __restrict__ Kdm,
    const float* __restrict__ BqT, const float* __restrict__ dec,
    float* __restrict__ core) {
  const int h = blockIdx.x >> 2;
  const int cg = blockIdx.x & 3;
  const int cbase = cg * 32;
  const int tid = threadIdx.x;

  __shared__ float Sm[128][36];
  __shared__ float um[64][36];
  __shared__ float buf[128 * 68];
  __shared__ float Bs[64][68];

  for (int i = tid; i < 128 * 36; i += 256) (&Sm[0][0])[i] = 0.f;

  const int t0 = (tid >> 3) * 2;       // u/O tile: 2t x 4c
  const int cc = (tid & 7) * 4;
  const int r0 = (tid >> 3) * 4;       // update tile: 4r x 4c
  __syncthreads();

  for (int ch = 0; ch < NC; ++ch) {
    const size_t cb = (size_t)h * NC + ch;
    const float* Wp = WpT + cb * 8192;
    const float* Qp = Qdt + cb * 8192;
    const float* Kp = Kdm + cb * 8192;
    const float* Up = Upre + cb * 8192;
    const float* Bp = BqT + cb * 4096;
    const float dC = dec[cb];

    // stage WpT [128][64] -> buf [128][68]; BqT -> Bs
#pragma unroll
    for (int i = 0; i < 8; ++i) {
      int w = (i * 256 + tid) * 4;
      *(float4*)&buf[(w >> 6) * 68 + (w & 63)] = *(const float4*)&Wp[w];
    }
#pragma unroll
    for (int i = 0; i < 4; ++i) {
      int w = (i * 256 + tid) * 4;
      *(float4*)&Bs[w >> 6][w & 63] = *(const float4*)&Bp[w];
    }
    __syncthreads();

    // u[t][c] = Upre[t][c] - sum_r WpT[r][t]*S[r][c]
    {
      float4 a0 = {0,0,0,0}, a1 = {0,0,0,0};
#pragma unroll 4
      for (int r = 0; r < 128; ++r) {
        float2 wv = *(const float2*)&buf[r * 68 + t0];
        float4 sv = *(const float4*)&Sm[r][cc];
        a0.x += wv.x * sv.x; a0.y += wv.x * sv.y; a0.z += wv.x * sv.z; a0.w += wv.x * sv.w;
        a1.x += wv.y * sv.x; a1.y += wv.y * sv.y; a1.z += wv.y * sv.z; a1.w += wv.y * sv.w;
      }
      float4 u0 = *(const float4*)&Up[(size_t)t0 * 128 + cbase + cc];
      float4 u1 = *(const float4*)&Up[(size_t)(t0 + 1) * 128 + cbase + cc];
      u0.x -= a0.x; u0.y -= a0.y; u0.z -= a0.z; u0.w -= a0.w;
      u1.x -= a1.x; u1.y -= a1.y; u1.z -= a1.z; u1.w -= a1.w;
      *(float4*)&um[t0][cc] = u0;
      *(float4*)&um[t0 + 1][cc] = u1;
    }
    __syncthreads();

    // stage Qdt -> buf
#pragma unroll
    for (int i = 0; i < 8; ++i) {
      int w = (i * 256 + tid) * 4;
      *(float4*)&buf[(w >> 6) * 68 + (w & 63)] = *(const float4*)&Qp[w];
    }
    __syncthreads();

    // O[t][c] = sum_r Qdt[r][t]*S[r][c] + sum_j BqT[j][t]*u[j][c]
    {
      float4 a0 = {0,0,0,0}, a1 = {0,0,0,0};
#pragma unroll 4
      for (int r = 0; r < 128; ++r) {
        float2 qv = *(const float2*)&buf[r * 68 + t0];
        float4 sv = *(const float4*)&Sm[r][cc];
        a0.x += qv.x * sv.x; a0.y += qv.x * sv.y; a0.z += qv.x * sv.z; a0.w += qv.x * sv.w;
        a1.x += qv.y * sv.x; a1.y += qv.y * sv.y; a1.z += qv.y * sv.z; a1.w += qv.y * sv.w;
      }
#pragma unroll 4
      for (int j = 0; j < 64; ++j) {
        float2 bv = *(const float2*)&Bs[j][t0];
        float4 uv = *(const float4*)&um[j][cc];
        a0.x += bv.x * uv.x; a0.y += bv.x * uv.y; a0.z += bv.x * uv.z; a0.w += bv.x * uv.w;
        a1.x += bv.y * uv.x; a1.y += bv.y * uv.y; a1.z += bv.y * uv.z; a1.w += bv.y * uv.w;
      }
      *(float4*)&core[(size_t)(ch * 64 + t0) * 1024 + h * 128 + cbase + cc] = a0;
      *(float4*)&core[(size_t)(ch * 64 + t0 + 1) * 1024 + h * 128 + cbase + cc] = a1;
    }
    __syncthreads();

    // stage Kd [64][128] -> buf [64][132]
#pragma unroll
    for (int i = 0; i < 8; ++i) {
      int w = (i * 256 + tid) * 4;
      *(float4*)&buf[(w >> 7) * 132 + (w & 127)] = *(const float4*)&Kp[w];
    }
    __syncthreads();

    // S[r][c] = dC*S[r][c] + sum_t Kd[t][r]*u[t][c]
    {
      float4 ac0 = {0,0,0,0}, ac1 = {0,0,0,0}, ac2 = {0,0,0,0}, ac3 = {0,0,0,0};
#pragma unroll 2
      for (int t = 0; t < 64; ++t) {
        float4 kv = *(const float4*)&buf[t * 132 + r0];
        float4 uv = *(const float4*)&um[t][cc];
        ac0.x += kv.x * uv.x; ac0.y += kv.x * uv.y; ac0.z += kv.x * uv.z; ac0.w += kv.x * uv.w;
        ac1.x += kv.y * uv.x; ac1.y += kv.y * uv.y; ac1.z += kv.y * uv.z; ac1.w += kv.y * uv.w;
        ac2.x += kv.z * uv.x; ac2.y += kv.z * uv.y; ac2.z += kv.z * uv.z; ac2.w += kv.z * uv.w;
        ac3.x += kv.w * uv.x; ac3.y += kv.w * uv.y; ac3.z += kv.w * uv.z; ac3.w += kv.w * uv.w;
      }
      float4 accs[4] = {ac0, ac1, ac2, ac3};
#pragma unroll
      for (int i = 0; i < 4; ++i) {
        float4 s = *(const float4*)&Sm[r0 + i][cc];
        s.x = dC * s.x + accs[i].x; s.y = dC * s.y + accs[i].y;
        s.z = dC * s.z + accs[i].z; s.w = dC * s.w + accs[i].w;
        *(float4*)&Sm[r0 + i][cc] = s;
      }
    }
    __syncthreads();
  }
}

// ---------------- gated RMSNorm per value head * silu(z); in-place safe
__global__ __launch_bounds__(256) void k_gatenorm(const float* __restrict__ core,
                                                  const float* __restrict__ qkvz,
                                                  const float* __restrict__ gnw,
                                                  float* __restrict__ y) {
  const int t = blockIdx.x, tid = threadIdx.x;
  const int wave = tid >> 6, lane = tid & 63;
  const int h = blockIdx.y * 4 + wave;
  const float* cbp = core + (size_t)t * 1024 + h * DV;
  float c0 = cbp[lane], c1 = cbp[lane + 64];
  float ss = c0 * c0 + c1 * c1;
  for (int m = 1; m < 64; m <<= 1) ss += __shfl_xor(ss, m);
  float scale = 1.f / sqrtf(ss * (1.0f / DV) + EPS);
  const float* zb = qkvz + (size_t)t * QKVZ_N + 2 * KEY_DIM + VAL_DIM + h * DV;
  float z0 = zb[lane], z1 = zb[lane + 64];
  float g0 = gnw[lane], g1 = gnw[lane + 64];
  float o0 = c0 * scale * g0 * (z0 / (1.f + expf(-z0)));
  float o1 = c1 * scale * g1 * (z1 / (1.f + expf(-z1)));
  float* yb = y + (size_t)t * 1024 + h * DV;
  yb[lane] = o0; yb[lane + 64] = o1;
}

// ---------------- router
__global__ __launch_bounds__(256) void k_router(const float* __restrict__ x2,
                                                const float* __restrict__ Wr,
                                                float* __restrict__ rinfo,
                                                int* __restrict__ cnt,
                                                float* __restrict__ outTopi) {
  const int t = blockIdx.x, tid = threadIdx.x;
  const int n = tid >> 5, kl = tid & 31;
  const float* xr = x2 + (size_t)t * HID;
  float s = 0.f;
  for (int k = kl; k < HID; k += 32) s += xr[k] * Wr[k * 8 + n];
  for (int m = 1; m < 32; m <<= 1) s += __shfl_xor(s, m);
  __shared__ float lg[8];
  if (kl == 0) lg[n] = s;
  __syncthreads();
  if (tid == 0) {
    int i0 = 0; float m0 = lg[0];
    for (int e = 1; e < 8; ++e) if (lg[e] > m0) { m0 = lg[e]; i0 = e; }
    int i1 = -1; float m1 = -1e30f;
    for (int e = 0; e < 8; ++e) if (e != i0 && lg[e] > m1) { m1 = lg[e]; i1 = e; }
    float e1 = expf(m1 - m0);
    float w0 = 1.f / (1.f + e1);
    float w1 = e1 / (1.f + e1);
    rinfo[t * 4 + 0] = (float)i0; rinfo[t * 4 + 1] = (float)i1;
    rinfo[t * 4 + 2] = w0;        rinfo[t * 4 + 3] = w1;
    atomicAdd(&cnt[i0], 1);
    atomicAdd(&cnt[i1], 1);
    outTopi[t * 2 + 0] = (float)i0;
    outTopi[t * 2 + 1] = (float)i1;
  }
}

__global__ void k_offsets(const int* __restrict__ cnt, int* __restrict__ offs,
                          int* __restrict__ cnt2) {
  if (threadIdx.x == 0) {
    int a = 0;
    for (int e = 0; e < 8; ++e) { offs[e] = a; a += cnt[e]; cnt2[e] = 0; }
  }
}

__global__ __launch_bounds__(256) void k_scatter(const float* __restrict__ rinfo,
                                                 const int* __restrict__ offs,
                                                 int* __restrict__ cnt2,
                                                 int* __restrict__ pairTok,
                                                 float* __restrict__ pairW) {
  int t = blockIdx.x * 256 + threadIdx.x;
  if (t >= S) return;
  int i0 = (int)rinfo[t * 4 + 0], i1 = (int)rinfo[t * 4 + 1];
  float w0 = rinfo[t * 4 + 2], w1 = rinfo[t * 4 + 3];
  int p0 = offs[i0] + atomicAdd(&cnt2[i0], 1);
  pairTok[p0] = t; pairW[p0] = w0;
  int p1 = offs[i1] + atomicAdd(&cnt2[i1], 1);
  pairTok[p1] = t; pairW[p1] = w1;
}

// ---------------- MoE stage 1
__global__ __launch_bounds__(256) void k_moe1(const float* __restrict__ x2,
                                              const float* __restrict__ Wg,
                                              const float* __restrict__ Wu,
                                              const int* __restrict__ offs,
                                              const int* __restrict__ cnt,
                                              const int* __restrict__ pairTok,
                                              float* __restrict__ act) {
  const int e = blockIdx.z;
  const int count = cnt[e];
  const int m0 = blockIdx.y * 64;
  if (m0 >= count) return;
  const int n0 = blockIdx.x * 64;
  const int base = offs[e];
  __shared__ float As[16][68], Bg[16][68], Bu[16][68];
  __shared__ int toks[64];
  const int tid = threadIdx.x;
  if (tid < 64) toks[tid] = (m0 + tid < count) ? pairTok[base + m0 + tid] : 0;
  __syncthreads();
  const float* WgB = Wg + (size_t)e * HID * INTER;
  const float* WuB = Wu + (size_t)e * HID * INTER;
  float accg[4][4] = {}, accu[4][4] = {};
  const int tx = tid & 15, ty = tid >> 4;
  const int ar = tid >> 2, ak = (tid & 3) * 4;
  const int br = tid >> 4, bc = (tid & 15) * 4;
  const bool va = (m0 + ar) < count;
  for (int k0 = 0; k0 < HID; k0 += 16) {
    float4 av = va ? *(const float4*)&x2[(size_t)toks[ar] * HID + k0 + ak]
                   : make_float4(0.f, 0.f, 0.f, 0.f);
    As[ak + 0][ar] = av.x; As[ak + 1][ar] = av.y;
    As[ak + 2][ar] = av.z; As[ak + 3][ar] = av.w;
    *(float4*)&Bg[br][bc] = *(const float4*)&WgB[(size_t)(k0 + br) * INTER + n0 + bc];
    *(float4*)&Bu[br][bc] = *(const float4*)&WuB[(size_t)(k0 + br) * INTER + n0 + bc];
    __syncthreads();
#pragma unroll
    for (int kk = 0; kk < 16; ++kk) {
      float4 a = *(const float4*)&As[kk][ty * 4];
      float4 g = *(const float4*)&Bg[kk][tx * 4];
      float4 u = *(const float4*)&Bu[kk][tx * 4];
      accg[0][0] += a.x * g.x; accg[0][1] += a.x * g.y; accg[0][2] += a.x * g.z; accg[0][3] += a.x * g.w;
      accg[1][0] += a.y * g.x; accg[1][1] += a.y * g.y; accg[1][2] += a.y * g.z; accg[1][3] += a.y * g.w;
      accg[2][0] += a.z * g.x; accg[2][1] += a.z * g.y; accg[2][2] += a.z * g.z; accg[2][3] += a.z * g.w;
      accg[3][0] += a.w * g.x; accg[3][1] += a.w * g.y; accg[3][2] += a.w * g.z; accg[3][3] += a.w * g.w;
      accu[0][0] += a.x * u.x; accu[0][1] += a.x * u.y; accu[0][2] += a.x * u.z; accu[0][3] += a.x * u.w;
      accu[1][0] += a.y * u.x; accu[1][1] += a.y * u.y; accu[1][2] += a.y * u.z; accu[1][3] += a.y * u.w;
      accu[2][0] += a.z * u.x; accu[2][1] += a.z * u.y; accu[2][2] += a.z * u.z; accu[2][3] += a.z * u.w;
      accu[3][0] += a.w * u.x; accu[3][1] += a.w * u.y; accu[3][2] += a.w * u.z; accu[3][3] += a.w * u.w;
    }
    __syncthreads();
  }
#pragma unroll
  for (int i = 0; i < 4; ++i) {
    int r = ty * 4 + i;
    if (m0 + r < count) {
#pragma unroll
      for (int j = 0; j < 4; ++j) {
        float gv = accg[i][j], uv = accu[i][j];
        act[(size_t)(base + m0 + r) * INTER + n0 + tx * 4 + j] =
            gv / (1.f + expf(-gv)) * uv;
      }
    }
  }
}

// ---------------- MoE stage 2
__global__ __launch_bounds__(256) void k_moe2(const float* __restrict__ act,
                                              const float* __restrict__ Wd,
                                              const int* __restrict__ offs,
                                              const int* __restrict__ cnt,
                                              const int* __restrict__ pairTok,
                                              const float* __restrict__ pairW,
                                              float* __restrict__ out) {
  const int e = blockIdx.z;
  const int count = cnt[e];
  const int m0 = blockIdx.y * 64;
  if (m0 >= count) return;
  const int n0 = blockIdx.x * 64;
  const int base = offs[e];
  __shared__ float As[16][68], Bss[16][68];
  const int tid = threadIdx.x;
  const int tx = tid & 15, ty = tid >> 4;
  const int ar = tid >> 2, ak = (tid & 3) * 4;
  const int br = tid >> 4, bc = (tid & 15) * 4;
  const bool va = (m0 + ar) < count;
  const float* WdB = Wd + (size_t)e * INTER * HID;
  float acc[4][4] = {};
  for (int k0 = 0; k0 < INTER; k0 += 16) {
    float4 av = va ? *(const float4*)&act[(size_t)(base + m0 + ar) * INTER + k0 + ak]
                   : make_float4(0.f, 0.f, 0.f, 0.f);
    As[ak + 0][ar] = av.x; As[ak + 1][ar] = av.y;
    As[ak + 2][ar] = av.z; As[ak + 3][ar] = av.w;
    *(float4*)&Bss[br][bc] = *(const float4*)&WdB[(size_t)(k0 + br) * HID + n0 + bc];
    __syncthreads();
#pragma unroll
    for (int kk = 0; kk < 16; ++kk) {
      float4 a = *(const float4*)&As[kk][ty * 4];
      float4 b = *(const float4*)&Bss[kk][tx * 4];
      acc[0][0] += a.x * b.x; acc[0][1] += a.x * b.y; acc[0][2] += a.x * b.z; acc[0][3] += a.x * b.w;
      acc[1][0] += a.y * b.x; acc[1][1] += a.y * b.y; acc[1][2] += a.y * b.z; acc[1][3] += a.y * b.w;
      acc[2][0] += a.z * b.x; acc[2][1] += a.z * b.y; acc[2][2] += a.z * b.z; acc[2][3] += a.z * b.w;
      acc[3][0] += a.w * b.x; acc[3][1] += a.w * b.y; acc[3][2] += a.w * b.z; acc[3][3] += a.w * b.w;
    }
    __syncthreads();
  }
#pragma unroll
  for (int i = 0; i < 4; ++i) {
    int r = ty * 4 + i;
    if (m0 + r < count) {
      int tok = pairTok[base + m0 + r];
      float w = pairW[base + m0 + r];
#pragma unroll
      for (int j = 0; j < 4; ++j)
        atomicAdd(&out[(size_t)tok * HID + n0 + tx * 4 + j], acc[i][j] * w);
    }
  }
}

extern "C" void kernel_launch(void* const* d_in, const int* in_sizes, int n_in,
                              void* d_out, int out_size, void* d_ws, size_t ws_size,
                              hipStream_t stream) {
  const float* hid      = (const float*)d_in[0];
  const float* w_ln1    = (const float*)d_in[1];
  const float* w_ln2    = (const float*)d_in[2];
  const float* W_qkvz   = (const float*)d_in[3];
  const float* W_ba     = (const float*)d_in[4];
  const float* conv_w   = (const float*)d_in[5];
  const float* dt_bias  = (const float*)d_in[6];
  const float* A_log    = (const float*)d_in[7];
  const float* gnw      = (const float*)d_in[8];
  const float* W_out    = (const float*)d_in[9];
  const float* W_router = (const float*)d_in[10];
  const float* W_gate   = (const float*)d_in[11];
  const float* W_up     = (const float*)d_in[12];
  const float* W_down   = (const float*)d_in[13];

  float* ws = (float*)d_ws;
  const size_t N1 = (size_t)S * HID;
  float* x1    = ws;
  float* qkvz  = x1 + N1;
  float* conv  = qkvz + (size_t)S * QKVZ_N;
  float* qn    = conv + (size_t)S * CONV_DIM;
  float* kn    = qn + N1;
  float* core  = kn + N1;
  float* Upre  = core + N1;
  float* WpT   = Upre + (size_t)HV * NC * 8192;
  float* Qdt   = WpT + (size_t)HV * NC * 8192;
  float* Kdm   = Qdt + (size_t)HV * NC * 8192;
  float* BqT   = Kdm + (size_t)HV * NC * 8192;
  float* dec   = BqT + (size_t)HV * NC * 4096;
  float* ba    = dec + 256;
  float* gb    = ba + (size_t)S * 16;
  float* betab = gb + (size_t)S * HV;
  float* rinfo = betab + (size_t)S * HV;
  float* pairW = rinfo + (size_t)S * 4;
  int*   ints  = (int*)(pairW + 4096);
  int* cnt = ints;
  int* cnt2 = ints + 8;
  int* offs = ints + 16;
  int* pairTok = ints + 32;
  float* x2 = x1;
  float* act = conv;
  float* y = core;

  float* outF = (float*)d_out;

  hipMemsetAsync(cnt, 0, 16 * sizeof(int), stream);

  k_rms<<<S, 256, 0, stream>>>(hid, w_ln1, x1);
  k_sgemm<<<dim3(QKVZ_N / 64, S / 64), 256, 0, stream>>>(x1, W_qkvz, nullptr, qkvz,
                                                         S, QKVZ_N, HID);
  k_ba<<<S, 256, 0, stream>>>(x1, W_ba, ba);
  k_bg<<<(S * HV + 255) / 256, 256, 0, stream>>>(ba, dt_bias, A_log, gb, betab);
  k_conv<<<(S * CONV_DIM) / 256, 256, 0, stream>>>(qkvz, conv_w, conv);
  k_prep<<<S, 512, 0, stream>>>(conv, qn, kn);
  k_chunkA<<<HV * NC, 256, 0, stream>>>(qn, kn, conv, gb, betab,
                                        Upre, WpT, Qdt, Kdm, BqT, dec);
  k_chunkB<<<32, 256, 0, stream>>>(Upre, WpT, Qdt, Kdm, BqT, dec, core);
  k_gatenorm<<<dim3(S, 2), 256, 0, stream>>>(core, qkvz, gnw, y);
  k_sgemm<<<dim3(HID / 64, S / 64), 256, 0, stream>>>(y, W_out, hid, outF,
                                                      S, HID, VAL_DIM);
  k_rms<<<S, 256, 0, stream>>>(outF, w_ln2, x2);
  k_router<<<S, 256, 0, stream>>>(x2, W_router, rinfo, cnt, outF + N1);
  k_offsets<<<1, 64, 0, stream>>>(cnt, offs, cnt2);
  k_scatter<<<(S + 255) / 256, 256, 0, stream>>>(rinfo, offs, cnt2, pairTok, pairW);
  k_moe1<<<dim3(INTER / 64, S / 64, NEXP), 256, 0, stream>>>(x2, W_gate, W_up, offs,
                                                             cnt, pairTok, act);
  k_moe2<<<dim3(HID / 64, S / 64, NEXP), 256, 0, stream>>>(act, W_down, offs, cnt,
                                                           pairTok, pairW, outF);
}

// Round 6
// 1133.248 us; speedup vs baseline: 1.8286x; 1.2396x over previous
//
#include <hip/hip_runtime.h>

#define S 2048
#define HID 1024
#define HK 4
#define HV 8
#define DK 128
#define DV 128
#define KEY_DIM 512
#define VAL_DIM 1024
#define CONV_DIM 2048
#define QKVZ_N 3072
#define NEXP 8
#define INTER 512
#define EPS 1e-6f
#define CK 64
#define NC 32

typedef unsigned short u16;
typedef unsigned int u32;
typedef __attribute__((ext_vector_type(8))) short bf16x8;
typedef __attribute__((ext_vector_type(4))) float f32x4;

__device__ __forceinline__ u16 f2b(float f) {
  u32 u = __builtin_bit_cast(u32, f);
  u += 0x7fff + ((u >> 16) & 1);
  return (u16)(u >> 16);
}

__device__ __forceinline__ void gload16(const u16* g, u16* l) {
  __builtin_amdgcn_global_load_lds(
      (const __attribute__((address_space(1))) void*)g,
      (__attribute__((address_space(3))) void*)l, 16, 0, 0);
}

// ---------------- zero-centered RMSNorm -> f32 out + bf16 out
__global__ __launch_bounds__(256) void k_rms(const float* __restrict__ x,
                                             const float* __restrict__ w,
                                             float* __restrict__ out,
                                             u16* __restrict__ outb) {
  const int row = blockIdx.x;
  const int tid = threadIdx.x;
  const float* xr = x + (size_t)row * HID;
  float4 v = ((const float4*)xr)[tid];
  float ss = v.x*v.x + v.y*v.y + v.z*v.z + v.w*v.w;
  for (int m = 1; m < 64; m <<= 1) ss += __shfl_xor(ss, m);
  __shared__ float sred[4];
  if ((tid & 63) == 0) sred[tid >> 6] = ss;
  __syncthreads();
  float tot = sred[0] + sred[1] + sred[2] + sred[3];
  float scale = 1.0f / sqrtf(tot * (1.0f / HID) + EPS);
  float4 wv = ((const float4*)w)[tid];
  float4 o;
  o.x = v.x * scale * (1.0f + wv.x);
  o.y = v.y * scale * (1.0f + wv.y);
  o.z = v.z * scale * (1.0f + wv.z);
  o.w = v.w * scale * (1.0f + wv.w);
  ((float4*)(out + (size_t)row * HID))[tid] = o;
  u32 p0 = (u32)f2b(o.x) | ((u32)f2b(o.y) << 16);
  u32 p1 = (u32)f2b(o.z) | ((u32)f2b(o.w) << 16);
  *(uint2*)&outb[(size_t)row * HID + tid * 4] = make_uint2(p0, p1);
}

// ---------------- transpose+cast: src f32 [K][N] -> dst bf16 [N][K], batched z
__global__ __launch_bounds__(256) void k_transp(const float* __restrict__ src,
                                                u16* __restrict__ dst,
                                                int K, int N) {
  __shared__ float t[32][33];
  const size_t bo = (size_t)blockIdx.z * K * N;
  src += bo; dst += bo;
  int n0 = blockIdx.x * 32, k0 = blockIdx.y * 32;
  int tx = threadIdx.x & 31, ty = threadIdx.x >> 5;
#pragma unroll
  for (int i = 0; i < 32; i += 8)
    t[ty + i][tx] = src[(size_t)(k0 + ty + i) * N + n0 + tx];
  __syncthreads();
#pragma unroll
  for (int i = 0; i < 32; i += 8)
    dst[(size_t)(n0 + ty + i) * K + k0 + tx] = f2b(t[tx][ty + i]);
}

// ---------------- f32 GEMM 128x128 tile, 8x8/thread: C = (Cadd?) + A[M,K]@B[K,N]
__global__ __launch_bounds__(256) void k_sgemm2(const float* __restrict__ A,
                                                const float* __restrict__ B,
                                                const float* __restrict__ Cadd,
                                                float* __restrict__ C,
                                                int M, int N, int K) {
  __shared__ float As[16][132];
  __shared__ float Bs[16][132];
  const int tid = threadIdx.x;
  const int ty = tid >> 4, tx = tid & 15;
  const int m0 = blockIdx.y * 128, n0 = blockIdx.x * 128;
  const int ar = tid >> 1, ak = (tid & 1) * 8;
  const int br = tid >> 4, bc = (tid & 15) * 8;
  float acc[8][8] = {};
  for (int k0 = 0; k0 < K; k0 += 16) {
    float4 a0 = *(const float4*)&A[(size_t)(m0 + ar) * K + k0 + ak];
    float4 a1 = *(const float4*)&A[(size_t)(m0 + ar) * K + k0 + ak + 4];
    As[ak + 0][ar] = a0.x; As[ak + 1][ar] = a0.y;
    As[ak + 2][ar] = a0.z; As[ak + 3][ar] = a0.w;
    As[ak + 4][ar] = a1.x; As[ak + 5][ar] = a1.y;
    As[ak + 6][ar] = a1.z; As[ak + 7][ar] = a1.w;
    *(float4*)&Bs[br][bc]     = *(const float4*)&B[(size_t)(k0 + br) * N + n0 + bc];
    *(float4*)&Bs[br][bc + 4] = *(const float4*)&B[(size_t)(k0 + br) * N + n0 + bc + 4];
    __syncthreads();
#pragma unroll
    for (int kk = 0; kk < 16; ++kk) {
      float4 aA = *(const float4*)&As[kk][ty * 8];
      float4 aB = *(const float4*)&As[kk][ty * 8 + 4];
      float4 bA = *(const float4*)&Bs[kk][tx * 8];
      float4 bB = *(const float4*)&Bs[kk][tx * 8 + 4];
      float a[8] = {aA.x, aA.y, aA.z, aA.w, aB.x, aB.y, aB.z, aB.w};
      float b[8] = {bA.x, bA.y, bA.z, bA.w, bB.x, bB.y, bB.z, bB.w};
#pragma unroll
      for (int i = 0; i < 8; ++i)
#pragma unroll
        for (int j = 0; j < 8; ++j) acc[i][j] += a[i] * b[j];
    }
    __syncthreads();
  }
#pragma unroll
  for (int i = 0; i < 8; ++i) {
    size_t off = (size_t)(m0 + ty * 8 + i) * N + n0 + tx * 8;
    float4 o0 = {acc[i][0], acc[i][1], acc[i][2], acc[i][3]};
    float4 o1 = {acc[i][4], acc[i][5], acc[i][6], acc[i][7]};
    if (Cadd) {
      float4 c0 = *(const float4*)&Cadd[off];
      float4 c1 = *(const float4*)&Cadd[off + 4];
      o0.x += c0.x; o0.y += c0.y; o0.z += c0.z; o0.w += c0.w;
      o1.x += c1.x; o1.y += c1.y; o1.z += c1.z; o1.w += c1.w;
    }
    *(float4*)&C[off] = o0;
    *(float4*)&C[off + 4] = o1;
  }
}

// ---------------- ba = x1 @ W_ba  (N=16)
__global__ __launch_bounds__(256) void k_ba(const float* __restrict__ x1,
                                            const float* __restrict__ Wba,
                                            float* __restrict__ ba) {
  const int t = blockIdx.x, tid = threadIdx.x;
  const int n = tid >> 4, kl = tid & 15;
  const float* xr = x1 + (size_t)t * HID;
  float s = 0.f;
  for (int k = kl; k < HID; k += 16) s += xr[k] * Wba[k * 16 + n];
  for (int m = 1; m < 16; m <<= 1) s += __shfl_xor(s, m);
  if (kl == 0) ba[t * 16 + n] = s;
}

// ---------------- beta = sigmoid(b); g = -exp(A_log)*softplus(a+dt_bias)
__global__ __launch_bounds__(256) void k_bg(const float* __restrict__ ba,
                                            const float* __restrict__ dt_bias,
                                            const float* __restrict__ A_log,
                                            float* __restrict__ gb,
                                            float* __restrict__ beta) {
  int i = blockIdx.x * 256 + threadIdx.x;
  if (i >= S * HV) return;
  int t = i >> 3, h = i & 7;
  float b = ba[t * 16 + h];
  float a = ba[t * 16 + 8 + h];
  beta[i] = 1.f / (1.f + expf(-b));
  float x = a + dt_bias[h];
  float sp = fmaxf(x, 0.f) + log1pf(expf(-fabsf(x)));
  gb[i] = -expf(A_log[h]) * sp;
}

// ---------------- causal depthwise conv (K=4) + silu on qkvz cols [0,2048)
__global__ __launch_bounds__(256) void k_conv(const float* __restrict__ qkvz,
                                              const float* __restrict__ cw,
                                              float* __restrict__ conv) {
  int idx = blockIdx.x * 256 + threadIdx.x;
  int t = idx >> 11, c = idx & 2047;
  float4 w = ((const float4*)cw)[c];
  float acc = 0.f;
  if (t >= 3) {
    acc = qkvz[(size_t)(t - 3) * QKVZ_N + c] * w.x
        + qkvz[(size_t)(t - 2) * QKVZ_N + c] * w.y
        + qkvz[(size_t)(t - 1) * QKVZ_N + c] * w.z
        + qkvz[(size_t)(t    ) * QKVZ_N + c] * w.w;
  } else {
    if (t - 3 >= 0) acc += qkvz[(size_t)(t - 3) * QKVZ_N + c] * w.x;
    if (t - 2 >= 0) acc += qkvz[(size_t)(t - 2) * QKVZ_N + c] * w.y;
    if (t - 1 >= 0) acc += qkvz[(size_t)(t - 1) * QKVZ_N + c] * w.z;
    acc += qkvz[(size_t)t * QKVZ_N + c] * w.w;
  }
  conv[idx] = acc / (1.f + expf(-acc));
}

// ---------------- l2-normalize q,k per source head; repeat to 8 dest heads
__global__ __launch_bounds__(512) void k_prep(const float* __restrict__ conv,
                                              float* __restrict__ qn,
                                              float* __restrict__ kn) {
  const int t = blockIdx.x, tid = threadIdx.x;
  const int sh = tid >> 7;
  const int d = tid & 127;
  float qv = conv[(size_t)t * CONV_DIM + sh * DK + d];
  float kv = conv[(size_t)t * CONV_DIM + KEY_DIM + sh * DK + d];
  float sq = qv * qv, sk = kv * kv;
  for (int m = 1; m < 64; m <<= 1) { sq += __shfl_xor(sq, m); sk += __shfl_xor(sk, m); }
  __shared__ float rq[8], rk[8];
  const int wave = tid >> 6;
  if ((tid & 63) == 0) { rq[wave] = sq; rk[wave] = sk; }
  __syncthreads();
  float sumq = rq[sh * 2] + rq[sh * 2 + 1];
  float sumk = rk[sh * 2] + rk[sh * 2 + 1];
  float qs = (1.f / sqrtf(sumq + EPS)) * 0.08838834764831845f;
  float ks = 1.f / sqrtf(sumk + EPS);
  float qo = qv * qs, ko = kv * ks;
  size_t b0 = (size_t)t * 1024 + (size_t)(sh * 2) * DK + d;
  qn[b0] = qo; qn[b0 + DK] = qo;
  kn[b0] = ko; kn[b0 + DK] = ko;
}

// ================= chunked gated delta rule =================
__global__ __launch_bounds__(256) void k_chunkA(
    const float* __restrict__ qn, const float* __restrict__ kn,
    const float* __restrict__ conv, const float* __restrict__ gbuf,
    const float* __restrict__ betab,
    float* __restrict__ Upre, float* __restrict__ WpT,
    float* __restrict__ Qdt, float* __restrict__ Kdm,
    float* __restrict__ BqT, float* __restrict__ dec) {
  const int h = blockIdx.x >> 5;
  const int ch = blockIdx.x & 31;
  const int tid = threadIdx.x;
  const int t_base = ch * CK;

  __shared__ float KT[128][68];
  __shared__ float UB[8704];
  __shared__ float Am[64][68];
  __shared__ float Mm[64][68];
  __shared__ float c_l[64], b_l[64], sW[64], seQ[64], sKd[64];

#pragma unroll
  for (int i = 0; i < 8; ++i) {
    int w = (i * 256 + tid) * 4;
    int tt = w >> 7, r = w & 127;
    float4 v = *(const float4*)&kn[(size_t)(t_base + tt) * 1024 + h * 128 + r];
    KT[r + 0][tt] = v.x; KT[r + 1][tt] = v.y; KT[r + 2][tt] = v.z; KT[r + 3][tt] = v.w;
  }
  if (tid < 64) {
    c_l[tid] = gbuf[(t_base + tid) * HV + h];
    b_l[tid] = betab[(t_base + tid) * HV + h];
  }
  __syncthreads();
  if (tid == 0) {
    float run = 0.f;
    for (int t = 0; t < 64; ++t) { run += c_l[t]; c_l[t] = run; }
    dec[h * NC + ch] = expf(run);
  }
  __syncthreads();
  if (tid < 64) {
    sW[tid] = b_l[tid] * expf(c_l[tid]);
    seQ[tid] = expf(c_l[tid]);
    sKd[tid] = expf(c_l[63] - c_l[tid]);
  }
  __syncthreads();

  {
    const int t0 = (tid >> 4) * 4, j0 = (tid & 15) * 4;
    float acc[4][4] = {};
    for (int r = 0; r < 128; ++r) {
      float4 a = *(const float4*)&KT[r][t0];
      float4 b = *(const float4*)&KT[r][j0];
      float av[4] = {a.x, a.y, a.z, a.w};
      float bv[4] = {b.x, b.y, b.z, b.w};
#pragma unroll
      for (int i = 0; i < 4; ++i)
#pragma unroll
        for (int j = 0; j < 4; ++j) acc[i][j] += av[i] * bv[j];
    }
#pragma unroll
    for (int i = 0; i < 4; ++i)
#pragma unroll
      for (int j = 0; j < 4; ++j) {
        int t = t0 + i, jj = j0 + j;
        Am[t][jj] = (jj < t) ? b_l[t] * expf(c_l[t] - c_l[jj]) * acc[i][j] : 0.f;
      }
  }
  __syncthreads();

  if (tid < 64) {
    const int c = tid;
    Mm[0][c] = (c == 0) ? 1.f : 0.f;
    for (int t = 1; t < 64; ++t) {
      float a = (c == t) ? 1.f : 0.f;
      for (int j = 0; j < t; ++j) a -= Am[t][j] * Mm[j][c];
      Mm[t][c] = a;
    }
  }
  __syncthreads();

  float* Vsm = UB;
#pragma unroll
  for (int i = 0; i < 8; ++i) {
    int w = (i * 256 + tid) * 4;
    int j = w >> 7, cc = w & 127;
    float4 v = *(const float4*)&conv[(size_t)(t_base + j) * CONV_DIM + 1024 + h * 128 + cc];
    float bj = b_l[j];
    v.x *= bj; v.y *= bj; v.z *= bj; v.w *= bj;
    *(float4*)&Vsm[j * 132 + cc] = v;
  }
  __syncthreads();

  const size_t cb = (size_t)h * NC + ch;
  {
    const int t0 = (tid >> 4) * 4, c0 = (tid & 15) * 8;
    float acc[4][8] = {};
    for (int j = 0; j < 64; ++j) {
      float m[4];
#pragma unroll
      for (int i = 0; i < 4; ++i) m[i] = Mm[t0 + i][j];
      float4 va = *(const float4*)&Vsm[j * 132 + c0];
      float4 vb = *(const float4*)&Vsm[j * 132 + c0 + 4];
      float v[8] = {va.x, va.y, va.z, va.w, vb.x, vb.y, vb.z, vb.w};
#pragma unroll
      for (int i = 0; i < 4; ++i)
#pragma unroll
        for (int c = 0; c < 8; ++c) acc[i][c] += m[i] * v[c];
    }
#pragma unroll
    for (int i = 0; i < 4; ++i) {
      float4 o0 = {acc[i][0], acc[i][1], acc[i][2], acc[i][3]};
      float4 o1 = {acc[i][4], acc[i][5], acc[i][6], acc[i][7]};
      *(float4*)&Upre[cb * 8192 + (size_t)(t0 + i) * 128 + c0] = o0;
      *(float4*)&Upre[cb * 8192 + (size_t)(t0 + i) * 128 + c0 + 4] = o1;
    }
  }
  {
    const int r0 = (tid >> 3) * 4, t0 = (tid & 7) * 8;
    float acc[4][8] = {};
    for (int j = 0; j < 64; ++j) {
      float s = sW[j];
      float kk[4];
#pragma unroll
      for (int i = 0; i < 4; ++i) kk[i] = KT[r0 + i][j] * s;
      float m[8];
#pragma unroll
      for (int t = 0; t < 8; ++t) m[t] = Mm[t0 + t][j];
#pragma unroll
      for (int i = 0; i < 4; ++i)
#pragma unroll
        for (int t = 0; t < 8; ++t) acc[i][t] += kk[i] * m[t];
    }
#pragma unroll
    for (int i = 0; i < 4; ++i) {
      float4 o0 = {acc[i][0], acc[i][1], acc[i][2], acc[i][3]};
      float4 o1 = {acc[i][4], acc[i][5], acc[i][6], acc[i][7]};
      *(float4*)&WpT[cb * 8192 + (size_t)(r0 + i) * 64 + t0] = o0;
      *(float4*)&WpT[cb * 8192 + (size_t)(r0 + i) * 64 + t0 + 4] = o1;
    }
  }
  __syncthreads();

  float* QT = UB;
#pragma unroll
  for (int i = 0; i < 8; ++i) {
    int w = (i * 256 + tid) * 4;
    int tt = w >> 7, r = w & 127;
    float4 v = *(const float4*)&qn[(size_t)(t_base + tt) * 1024 + h * 128 + r];
    QT[(r + 0) * 68 + tt] = v.x; QT[(r + 1) * 68 + tt] = v.y;
    QT[(r + 2) * 68 + tt] = v.z; QT[(r + 3) * 68 + tt] = v.w;
  }
  __syncthreads();

  {
    const int t0 = (tid >> 4) * 4, j0 = (tid & 15) * 4;
    float acc[4][4] = {};
    for (int r = 0; r < 128; ++r) {
      float4 a = *(const float4*)&QT[r * 68 + t0];
      float4 b = *(const float4*)&KT[r][j0];
      float av[4] = {a.x, a.y, a.z, a.w};
      float bv[4] = {b.x, b.y, b.z, b.w};
#pragma unroll
      for (int i = 0; i < 4; ++i)
#pragma unroll
        for (int j = 0; j < 4; ++j) acc[i][j] += av[i] * bv[j];
    }
#pragma unroll
    for (int i = 0; i < 4; ++i)
#pragma unroll
      for (int j = 0; j < 4; ++j) {
        int t = t0 + i, jj = j0 + j;
        BqT[cb * 4096 + (size_t)jj * 64 + t] =
            (jj <= t) ? expf(c_l[t] - c_l[jj]) * acc[i][j] : 0.f;
      }
  }
#pragma unroll
  for (int i = 0; i < 8; ++i) {
    int w = (i * 256 + tid) * 4;
    int r = w >> 6, t = w & 63;
    float4 q = *(const float4*)&QT[r * 68 + t];
    float4 s = *(const float4*)&seQ[t];
    q.x *= s.x; q.y *= s.y; q.z *= s.z; q.w *= s.w;
    *(float4*)&Qdt[cb * 8192 + w] = q;
  }
#pragma unroll
  for (int i = 0; i < 8; ++i) {
    int w = (i * 256 + tid) * 4;
    int t = w >> 7, r = w & 127;
    float s = sKd[t];
    float4 o;
    o.x = KT[r + 0][t] * s; o.y = KT[r + 1][t] * s;
    o.z = KT[r + 2][t] * s; o.w = KT[r + 3][t] * s;
    *(float4*)&Kdm[cb * 8192 + w] = o;
  }
}

// Phase B: sequential over chunks. 64 blocks = 8 heads x 8 col-groups (16 cols).
__global__ __launch_bounds__(256) void k_chunkB(
    const float* __restrict__ Upre, const float* __restrict__ WpT,
    const float* __restrict__ Qdt, const float* __restrict__ Kdm,
    const float* __restrict__ BqT, const float* __restrict__ dec,
    float* __restrict__ core) {
  const int h = blockIdx.x >> 3;
  const int cg = blockIdx.x & 7;
  const int cbase = cg * 16;
  const int tid = threadIdx.x;

  __shared__ float Sm[128][20];
  __shared__ float um[64][20];
  __shared__ float buf[128 * 68];
  __shared__ float Bs[64][68];

  for (int i = tid; i < 128 * 20; i += 256) (&Sm[0][0])[i] = 0.f;

  const int t0 = (tid >> 3) * 2;       // u/O tile: 2t x 2c
  const int cc = (tid & 7) * 2;
  const int r0 = (tid >> 3) * 4;       // S tile: 4r x 2c
  __syncthreads();

  for (int ch = 0; ch < NC; ++ch) {
    const size_t cb = (size_t)h * NC + ch;
    const float* Wp = WpT + cb * 8192;
    const float* Qp = Qdt + cb * 8192;
    const float* Kp = Kdm + cb * 8192;
    const float* Up = Upre + cb * 8192;
    const float* Bp = BqT + cb * 4096;
    const float dC = dec[cb];

    // stage WpT [128][64] -> buf[r*68+t]; BqT [64][64] -> Bs
#pragma unroll
    for (int i = 0; i < 8; ++i) {
      int w = (i * 256 + tid) * 4;
      *(float4*)&buf[(w >> 6) * 68 + (w & 63)] = *(const float4*)&Wp[w];
    }
#pragma unroll
    for (int i = 0; i < 4; ++i) {
      int w = (i * 256 + tid) * 4;
      *(float4*)&Bs[w >> 6][w & 63] = *(const float4*)&Bp[w];
    }
    __syncthreads();

    // u[t][c] = Upre[t][c] - sum_r WpT[r][t]*S[r][c]
    {
      float a00 = 0, a01 = 0, a10 = 0, a11 = 0;
#pragma unroll 4
      for (int r = 0; r < 128; ++r) {
        float2 wv = *(const float2*)&buf[r * 68 + t0];
        float2 sv = *(const float2*)&Sm[r][cc];
        a00 += wv.x * sv.x; a01 += wv.x * sv.y;
        a10 += wv.y * sv.x; a11 += wv.y * sv.y;
      }
      float2 u0 = *(const float2*)&Up[(size_t)t0 * 128 + cbase + cc];
      float2 u1 = *(const float2*)&Up[(size_t)(t0 + 1) * 128 + cbase + cc];
      u0.x -= a00; u0.y -= a01;
      u1.x -= a10; u1.y -= a11;
      *(float2*)&um[t0][cc] = u0;
      *(float2*)&um[t0 + 1][cc] = u1;
    }
    __syncthreads();

    // stage Qdt [128][64] -> buf
#pragma unroll
    for (int i = 0; i < 8; ++i) {
      int w = (i * 256 + tid) * 4;
      *(float4*)&buf[(w >> 6) * 68 + (w & 63)] = *(const float4*)&Qp[w];
    }
    __syncthreads();

    // O[t][c] = sum_r Qdt[r][t]*S[r][c] + sum_j BqT[j][t]*u[j][c]
    {
      float a00 = 0, a01 = 0, a10 = 0, a11 = 0;
#pragma unroll 4
      for (int r = 0; r < 128; ++r) {
        float2 qv = *(const float2*)&buf[r * 68 + t0];
        float2 sv = *(const float2*)&Sm[r][cc];
        a00 += qv.x * sv.x; a01 += qv.x * sv.y;
        a10 += qv.y * sv.x; a11 += qv.y * sv.y;
      }
#pragma unroll 4
      for (int j = 0; j < 64; ++j) {
        float2 bv = *(const float2*)&Bs[j][t0];
        float2 uv = *(const float2*)&um[j][cc];
        a00 += bv.x * uv.x; a01 += bv.x * uv.y;
        a10 += bv.y * uv.x; a11 += bv.y * uv.y;
      }
      float2 o0 = {a00, a01}, o1 = {a10, a11};
      *(float2*)&core[(size_t)(ch * 64 + t0) * 1024 + h * 128 + cbase + cc] = o0;
      *(float2*)&core[(size_t)(ch * 64 + t0 + 1) * 1024 + h * 128 + cbase + cc] = o1;
    }
    __syncthreads();

    // stage Kd [64][128] -> buf[t*132+r]
#pragma unroll
    for (int i = 0; i < 8; ++i) {
      int w = (i * 256 + tid) * 4;
      *(float4*)&buf[(w >> 7) * 132 + (w & 127)] = *(const float4*)&Kp[w];
    }
    __syncthreads();

    // S[r][c] = dC*S[r][c] + sum_t Kd[t][r]*u[t][c]
    {
      float acc[4][2] = {};
#pragma unroll 2
      for (int t = 0; t < 64; ++t) {
        float4 kv = *(const float4*)&buf[t * 132 + r0];
        float2 uv = *(const float2*)&um[t][cc];
        acc[0][0] += kv.x * uv.x; acc[0][1] += kv.x * uv.y;
        acc[1][0] += kv.y * uv.x; acc[1][1] += kv.y * uv.y;
        acc[2][0] += kv.z * uv.x; acc[2][1] += kv.z * uv.y;
        acc[3][0] += kv.w * uv.x; acc[3][1] += kv.w * uv.y;
      }
#pragma unroll
      for (int i = 0; i < 4; ++i) {
        float2 s = *(const float2*)&Sm[r0 + i][cc];
        s.x = dC * s.x + acc[i][0];
        s.y = dC * s.y + acc[i][1];
        *(float2*)&Sm[r0 + i][cc] = s;
      }
    }
    __syncthreads();
  }
}

// ---------------- gated RMSNorm per value head * silu(z); in-place safe (f32)
__global__ __launch_bounds__(256) void k_gatenorm(const float* __restrict__ core,
                                                  const float* __restrict__ qkvz,
                                                  const float* __restrict__ gnw,
                                                  float* __restrict__ y) {
  const int t = blockIdx.x, tid = threadIdx.x;
  const int wave = tid >> 6, lane = tid & 63;
  const int h = blockIdx.y * 4 + wave;
  const float* cbp = core + (size_t)t * 1024 + h * DV;
  float c0 = cbp[lane], c1 = cbp[lane + 64];
  float ss = c0 * c0 + c1 * c1;
  for (int m = 1; m < 64; m <<= 1) ss += __shfl_xor(ss, m);
  float scale = 1.f / sqrtf(ss * (1.0f / DV) + EPS);
  const float* zb = qkvz + (size_t)t * QKVZ_N + 2 * KEY_DIM + VAL_DIM + h * DV;
  float z0 = zb[lane], z1 = zb[lane + 64];
  float g0 = gnw[lane], g1 = gnw[lane + 64];
  float o0 = c0 * scale * g0 * (z0 / (1.f + expf(-z0)));
  float o1 = c1 * scale * g1 * (z1 / (1.f + expf(-z1)));
  float* yb = y + (size_t)t * 1024 + h * DV;
  yb[lane] = o0; yb[lane + 64] = o1;
}

// ---------------- router
__global__ __launch_bounds__(256) void k_router(const float* __restrict__ x2,
                                                const float* __restrict__ Wr,
                                                float* __restrict__ rinfo,
                                                int* __restrict__ cnt,
                                                float* __restrict__ outTopi) {
  const int t = blockIdx.x, tid = threadIdx.x;
  const int n = tid >> 5, kl = tid & 31;
  const float* xr = x2 + (size_t)t * HID;
  float s = 0.f;
  for (int k = kl; k < HID; k += 32) s += xr[k] * Wr[k * 8 + n];
  for (int m = 1; m < 32; m <<= 1) s += __shfl_xor(s, m);
  __shared__ float lg[8];
  if (kl == 0) lg[n] = s;
  __syncthreads();
  if (tid == 0) {
    int i0 = 0; float m0 = lg[0];
    for (int e = 1; e < 8; ++e) if (lg[e] > m0) { m0 = lg[e]; i0 = e; }
    int i1 = -1; float m1 = -1e30f;
    for (int e = 0; e < 8; ++e) if (e != i0 && lg[e] > m1) { m1 = lg[e]; i1 = e; }
    float e1 = expf(m1 - m0);
    float w0 = 1.f / (1.f + e1);
    float w1 = e1 / (1.f + e1);
    rinfo[t * 4 + 0] = (float)i0; rinfo[t * 4 + 1] = (float)i1;
    rinfo[t * 4 + 2] = w0;        rinfo[t * 4 + 3] = w1;
    atomicAdd(&cnt[i0], 1);
    atomicAdd(&cnt[i1], 1);
    outTopi[t * 2 + 0] = (float)i0;
    outTopi[t * 2 + 1] = (float)i1;
  }
}

__global__ void k_offsets(const int* __restrict__ cnt, int* __restrict__ offs,
                          int* __restrict__ cnt2) {
  if (threadIdx.x == 0) {
    int a = 0;
    for (int e = 0; e < 8; ++e) { offs[e] = a; a += cnt[e]; cnt2[e] = 0; }
  }
}

__global__ __launch_bounds__(256) void k_scatter(const float* __restrict__ rinfo,
                                                 const int* __restrict__ offs,
                                                 int* __restrict__ cnt2,
                                                 int* __restrict__ pairTok,
                                                 int* __restrict__ tokPos) {
  int t = blockIdx.x * 256 + threadIdx.x;
  if (t >= S) return;
  int i0 = (int)rinfo[t * 4 + 0], i1 = (int)rinfo[t * 4 + 1];
  int p0 = offs[i0] + atomicAdd(&cnt2[i0], 1);
  pairTok[p0] = t;
  int p1 = offs[i1] + atomicAdd(&cnt2[i1], 1);
  pairTok[p1] = t;
  tokPos[t * 2 + 0] = p0;
  tokPos[t * 2 + 1] = p1;
}

// ---------------- MoE stage 1 (MFMA bf16)
__global__ __launch_bounds__(256) void k_moe1m(const u16* __restrict__ x2b,
                                               const u16* __restrict__ WgT,
                                               const u16* __restrict__ WuT,
                                               const int* __restrict__ offs,
                                               const int* __restrict__ cnt,
                                               const int* __restrict__ pairTok,
                                               u16* __restrict__ act) {
  const int e = blockIdx.z;
  const int count = cnt[e];
  const int m0 = blockIdx.y * 128;
  if (m0 >= count) return;
  const int base = offs[e];
  __shared__ u16 Abuf[4096], Gbuf[4096], Ubuf[4096];
  const int tid = threadIdx.x;
  const int lane = tid & 63, wave = tid >> 6;
  const int wm = wave >> 1, wn = wave & 1;
  const int n0 = blockIdx.x * 128;
  const int wb0 = wave * 512, wb1 = 2048 + wave * 512;
  const int r0 = tid >> 2;
  int mr0 = m0 + r0;       if (mr0 > count - 1) mr0 = count - 1;
  int mr1 = m0 + r0 + 64;  if (mr1 > count - 1) mr1 = count - 1;
  const int t0tok = pairTok[base + mr0];
  const int t1tok = pairTok[base + mr1];
  const u16* Ag0 = x2b + (size_t)t0tok * 1024 + (tid & 3) * 8;
  const u16* Ag1 = x2b + (size_t)t1tok * 1024 + (tid & 3) * 8;
  const u16* Gg0 = WgT + (size_t)e * 512 * 1024 + (size_t)(n0 + r0) * 1024 + (tid & 3) * 8;
  const u16* Gg1 = Gg0 + (size_t)64 * 1024;
  const u16* Ug0 = WuT + (size_t)e * 512 * 1024 + (size_t)(n0 + r0) * 1024 + (tid & 3) * 8;
  const u16* Ug1 = Ug0 + (size_t)64 * 1024;
  f32x4 ag[4][4] = {}, au[4][4] = {};
  const int fr = lane & 15, kg = lane >> 4;
  for (int k0 = 0; k0 < 1024; k0 += 32) {
    gload16(Ag0 + k0, Abuf + wb0);
    gload16(Ag1 + k0, Abuf + wb1);
    gload16(Gg0 + k0, Gbuf + wb0);
    gload16(Gg1 + k0, Gbuf + wb1);
    gload16(Ug0 + k0, Ubuf + wb0);
    gload16(Ug1 + k0, Ubuf + wb1);
    __syncthreads();
    bf16x8 af[4], gf[4], uf[4];
#pragma unroll
    for (int i = 0; i < 4; ++i) {
      af[i] = *(const bf16x8*)&Abuf[(wm * 64 + i * 16 + fr) * 32 + kg * 8];
      gf[i] = *(const bf16x8*)&Gbuf[(wn * 64 + i * 16 + fr) * 32 + kg * 8];
      uf[i] = *(const bf16x8*)&Ubuf[(wn * 64 + i * 16 + fr) * 32 + kg * 8];
    }
#pragma unroll
    for (int i = 0; i < 4; ++i)
#pragma unroll
      for (int j = 0; j < 4; ++j) {
        ag[i][j] = __builtin_amdgcn_mfma_f32_16x16x32_bf16(af[i], gf[j], ag[i][j], 0, 0, 0);
        au[i][j] = __builtin_amdgcn_mfma_f32_16x16x32_bf16(af[i], uf[j], au[i][j], 0, 0, 0);
      }
    __syncthreads();
  }
#pragma unroll
  for (int i = 0; i < 4; ++i) {
#pragma unroll
    for (int j = 0; j < 4; ++j) {
      int rowt = wm * 64 + i * 16 + kg * 4;
      int col = n0 + wn * 64 + j * 16 + fr;
#pragma unroll
      for (int r = 0; r < 4; ++r) {
        if (m0 + rowt + r < count) {
          float g = ag[i][j][r], u = au[i][j][r];
          act[(size_t)(base + m0 + rowt + r) * 512 + col] =
              f2b(g / (1.f + expf(-g)) * u);
        }
      }
    }
  }
}

// ---------------- MoE stage 2 (MFMA bf16): eo = act @ Wd[e]
__global__ __launch_bounds__(256) void k_moe2m(const u16* __restrict__ act,
                                               const u16* __restrict__ WdT,
                                               const int* __restrict__ offs,
                                               const int* __restrict__ cnt,
                                               float* __restrict__ eo) {
  const int e = blockIdx.z;
  const int count = cnt[e];
  const int m0 = blockIdx.y * 128;
  if (m0 >= count) return;
  const int base = offs[e];
  __shared__ u16 Abuf[4096], Bbuf[4096];
  const int tid = threadIdx.x;
  const int lane = tid & 63, wave = tid >> 6;
  const int wm = wave >> 1, wn = wave & 1;
  const int n0 = blockIdx.x * 128;
  const int wb0 = wave * 512, wb1 = 2048 + wave * 512;
  const int r0 = tid >> 2;
  int mr0 = m0 + r0;       if (mr0 > count - 1) mr0 = count - 1;
  int mr1 = m0 + r0 + 64;  if (mr1 > count - 1) mr1 = count - 1;
  const u16* Ag0 = act + (size_t)(base + mr0) * 512 + (tid & 3) * 8;
  const u16* Ag1 = act + (size_t)(base + mr1) * 512 + (tid & 3) * 8;
  const u16* Bg0 = WdT + (size_t)e * 1024 * 512 + (size_t)(n0 + r0) * 512 + (tid & 3) * 8;
  const u16* Bg1 = Bg0 + (size_t)64 * 512;
  f32x4 acc[4][4] = {};
  const int fr = lane & 15, kg = lane >> 4;
  for (int k0 = 0; k0 < 512; k0 += 32) {
    gload16(Ag0 + k0, Abuf + wb0);
    gload16(Ag1 + k0, Abuf + wb1);
    gload16(Bg0 + k0, Bbuf + wb0);
    gload16(Bg1 + k0, Bbuf + wb1);
    __syncthreads();
    bf16x8 af[4], bfr[4];
#pragma unroll
    for (int i = 0; i < 4; ++i) {
      af[i]  = *(const bf16x8*)&Abuf[(wm * 64 + i * 16 + fr) * 32 + kg * 8];
      bfr[i] = *(const bf16x8*)&Bbuf[(wn * 64 + i * 16 + fr) * 32 + kg * 8];
    }
#pragma unroll
    for (int i = 0; i < 4; ++i)
#pragma unroll
      for (int j = 0; j < 4; ++j)
        acc[i][j] = __builtin_amdgcn_mfma_f32_16x16x32_bf16(af[i], bfr[j], acc[i][j], 0, 0, 0);
    __syncthreads();
  }
#pragma unroll
  for (int i = 0; i < 4; ++i) {
#pragma unroll
    for (int j = 0; j < 4; ++j) {
      int rowt = wm * 64 + i * 16 + kg * 4;
      int col = n0 + wn * 64 + j * 16 + fr;
#pragma unroll
      for (int r = 0; r < 4; ++r) {
        if (m0 + rowt + r < count)
          eo[(size_t)(base + m0 + rowt + r) * 1024 + col] = acc[i][j][r];
      }
    }
  }
}

// ---------------- final: out[t] += w0*eo[p0] + w1*eo[p1]
__global__ __launch_bounds__(256) void k_finish(const float* __restrict__ eo,
                                                const int* __restrict__ tokPos,
                                                const float* __restrict__ rinfo,
                                                float* __restrict__ out) {
  const int t = blockIdx.x;
  const int c = threadIdx.x * 4;
  float w0 = rinfo[t * 4 + 2], w1 = rinfo[t * 4 + 3];
  int p0 = tokPos[t * 2 + 0], p1 = tokPos[t * 2 + 1];
  float4 a = *(const float4*)&eo[(size_t)p0 * 1024 + c];
  float4 b = *(const float4*)&eo[(size_t)p1 * 1024 + c];
  float4 o = *(const float4*)&out[(size_t)t * 1024 + c];
  o.x += w0 * a.x + w1 * b.x;
  o.y += w0 * a.y + w1 * b.y;
  o.z += w0 * a.z + w1 * b.z;
  o.w += w0 * a.w + w1 * b.w;
  *(float4*)&out[(size_t)t * 1024 + c] = o;
}

extern "C" void kernel_launch(void* const* d_in, const int* in_sizes, int n_in,
                              void* d_out, int out_size, void* d_ws, size_t ws_size,
                              hipStream_t stream) {
  const float* hid      = (const float*)d_in[0];
  const float* w_ln1    = (const float*)d_in[1];
  const float* w_ln2    = (const float*)d_in[2];
  const float* W_qkvz   = (const float*)d_in[3];
  const float* W_ba     = (const float*)d_in[4];
  const float* conv_w   = (const float*)d_in[5];
  const float* dt_bias  = (const float*)d_in[6];
  const float* A_log    = (const float*)d_in[7];
  const float* gnw      = (const float*)d_in[8];
  const float* W_out    = (const float*)d_in[9];
  const float* W_router = (const float*)d_in[10];
  const float* W_gate   = (const float*)d_in[11];
  const float* W_up     = (const float*)d_in[12];
  const float* W_down   = (const float*)d_in[13];

  float* ws = (float*)d_ws;
  const size_t M1 = (size_t)1024 * 1024;
  float* x1    = ws;               // 2M f32 (also x2)
  float* qkvz  = x1 + 2 * M1;      // 6M
  float* conv  = qkvz + 6 * M1;    // 4M
  float* qn    = conv + 4 * M1;    // 2M
  float* kn    = qn + 2 * M1;      // 2M
  float* core  = kn + 2 * M1;      // 2M (also y, in-place)
  float* Upre  = core + 2 * M1;    // 2M
  float* WpT   = Upre + 2 * M1;    // 2M
  float* Qdt   = WpT + 2 * M1;     // 2M
  float* Kdm   = Qdt + 2 * M1;     // 2M
  float* BqT   = Kdm + 2 * M1;     // 1M
  float* dec   = BqT + M1;         // 256
  float* ba    = dec + 256;        // 32768
  float* gb    = ba + 32768;       // 16384
  float* betab = gb + 16384;       // 16384
  float* rinfo = betab + 16384;    // 8192
  int*   ints  = (int*)(rinfo + 8192);
  int* cnt     = ints;             // 8
  int* cnt2    = ints + 8;         // 8
  int* offs    = ints + 16;        // 8
  int* pairTok = ints + 32;        // 4096
  int* tokPos  = ints + 4128;      // 4096
  u16* x1b     = (u16*)(ints + 8224);  // 2M u16

  // bf16 weight buffers overlaid on phase-dead f32 regions (valid after chunkA):
  u16* WgT = (u16*)conv;            // 4M u16
  u16* WuT = (u16*)(conv + 2 * M1); // 4M u16
  u16* WdT = (u16*)kn;              // 4M u16
  u16* act = (u16*)Kdm;             // 2M u16 (after chunkB)
  float* eo = Upre;                 // 4M f32 spans Upre+WpT (after chunkB)

  float* outF = (float*)d_out;
  const size_t N1 = (size_t)S * HID;

  hipMemsetAsync(cnt, 0, 16 * sizeof(int), stream);

  k_rms<<<S, 256, 0, stream>>>(hid, w_ln1, x1, x1b);
  k_sgemm2<<<dim3(24, 16), 256, 0, stream>>>(x1, W_qkvz, nullptr, qkvz, S, QKVZ_N, HID);
  k_ba<<<S, 256, 0, stream>>>(x1, W_ba, ba);
  k_bg<<<(S * HV + 255) / 256, 256, 0, stream>>>(ba, dt_bias, A_log, gb, betab);
  k_conv<<<(S * CONV_DIM) / 256, 256, 0, stream>>>(qkvz, conv_w, conv);
  k_prep<<<S, 512, 0, stream>>>(conv, qn, kn);
  k_chunkA<<<HV * NC, 256, 0, stream>>>(qn, kn, conv, gb, betab,
                                        Upre, WpT, Qdt, Kdm, BqT, dec);
  // conv/qn/kn dead -> build MoE bf16 weight buffers
  k_transp<<<dim3(16, 32, 8), 256, 0, stream>>>(W_gate, WgT, 1024, 512);
  k_transp<<<dim3(16, 32, 8), 256, 0, stream>>>(W_up, WuT, 1024, 512);
  k_transp<<<dim3(32, 16, 8), 256, 0, stream>>>(W_down, WdT, 512, 1024);
  k_chunkB<<<64, 256, 0, stream>>>(Upre, WpT, Qdt, Kdm, BqT, dec, core);
  k_gatenorm<<<dim3(S, 2), 256, 0, stream>>>(core, qkvz, gnw, core);
  k_sgemm2<<<dim3(8, 16), 256, 0, stream>>>(core, W_out, hid, outF, S, HID, VAL_DIM);
  k_rms<<<S, 256, 0, stream>>>(outF, w_ln2, x1, x1b);
  k_router<<<S, 256, 0, stream>>>(x1, W_router, rinfo, cnt, outF + N1);
  k_offsets<<<1, 64, 0, stream>>>(cnt, offs, cnt2);
  k_scatter<<<(S + 255) / 256, 256, 0, stream>>>(rinfo, offs, cnt2, pairTok, tokPos);
  k_moe1m<<<dim3(4, 32, 8), 256, 0, stream>>>(x1b, WgT, WuT, offs, cnt, pairTok, act);
  k_moe2m<<<dim3(8, 32, 8), 256, 0, stream>>>(act, WdT, offs, cnt, eo);
  k_finish<<<S, 256, 0, stream>>>(eo, tokPos, rinfo, outF);
}

// Round 7
// 1086.377 us; speedup vs baseline: 1.9075x; 1.0431x over previous
//
#include <hip/hip_runtime.h>

#define S 2048
#define HID 1024
#define HK 4
#define HV 8
#define DK 128
#define DV 128
#define KEY_DIM 512
#define VAL_DIM 1024
#define CONV_DIM 2048
#define QKVZ_N 3072
#define NEXP 8
#define INTER 512
#define EPS 1e-6f
#define CK 64
#define NC 32

typedef unsigned short u16;
typedef unsigned int u32;
typedef __attribute__((ext_vector_type(8))) short bf16x8;
typedef __attribute__((ext_vector_type(4))) float f32x4;

__device__ __forceinline__ u16 f2b(float f) {
  u32 u = __builtin_bit_cast(u32, f);
  u += 0x7fff + ((u >> 16) & 1);
  return (u16)(u >> 16);
}

__device__ __forceinline__ void gload16(const u16* g, u16* l) {
  __builtin_amdgcn_global_load_lds(
      (const __attribute__((address_space(1))) void*)g,
      (__attribute__((address_space(3))) void*)l, 16, 0, 0);
}

// ---------------- zero-centered RMSNorm -> f32 out + bf16 out
__global__ __launch_bounds__(256) void k_rms(const float* __restrict__ x,
                                             const float* __restrict__ w,
                                             float* __restrict__ out,
                                             u16* __restrict__ outb) {
  const int row = blockIdx.x;
  const int tid = threadIdx.x;
  const float* xr = x + (size_t)row * HID;
  float4 v = ((const float4*)xr)[tid];
  float ss = v.x*v.x + v.y*v.y + v.z*v.z + v.w*v.w;
  for (int m = 1; m < 64; m <<= 1) ss += __shfl_xor(ss, m);
  __shared__ float sred[4];
  if ((tid & 63) == 0) sred[tid >> 6] = ss;
  __syncthreads();
  float tot = sred[0] + sred[1] + sred[2] + sred[3];
  float scale = 1.0f / sqrtf(tot * (1.0f / HID) + EPS);
  float4 wv = ((const float4*)w)[tid];
  float4 o;
  o.x = v.x * scale * (1.0f + wv.x);
  o.y = v.y * scale * (1.0f + wv.y);
  o.z = v.z * scale * (1.0f + wv.z);
  o.w = v.w * scale * (1.0f + wv.w);
  ((float4*)(out + (size_t)row * HID))[tid] = o;
  u32 p0 = (u32)f2b(o.x) | ((u32)f2b(o.y) << 16);
  u32 p1 = (u32)f2b(o.z) | ((u32)f2b(o.w) << 16);
  *(uint2*)&outb[(size_t)row * HID + tid * 4] = make_uint2(p0, p1);
}

// ---------------- transpose+cast: src f32 [K][N] -> dst bf16 [N][K], batched z
__global__ __launch_bounds__(256) void k_transp(const float* __restrict__ src,
                                                u16* __restrict__ dst,
                                                int K, int N) {
  __shared__ float t[32][33];
  const size_t bo = (size_t)blockIdx.z * K * N;
  src += bo; dst += bo;
  int n0 = blockIdx.x * 32, k0 = blockIdx.y * 32;
  int tx = threadIdx.x & 31, ty = threadIdx.x >> 5;
#pragma unroll
  for (int i = 0; i < 32; i += 8)
    t[ty + i][tx] = src[(size_t)(k0 + ty + i) * N + n0 + tx];
  __syncthreads();
#pragma unroll
  for (int i = 0; i < 32; i += 8)
    dst[(size_t)(n0 + ty + i) * K + k0 + tx] = f2b(t[tx][ty + i]);
}

// ---------------- f32 GEMM 128x128 tile, 8x8/thread, reg-double-buffered
__global__ __launch_bounds__(256) void k_sgemm2(const float* __restrict__ A,
                                                const float* __restrict__ B,
                                                const float* __restrict__ Cadd,
                                                float* __restrict__ C,
                                                int M, int N, int K) {
  __shared__ float As[16][132];
  __shared__ float Bs[16][132];
  const int tid = threadIdx.x;
  const int ty = tid >> 4, tx = tid & 15;
  const int m0 = blockIdx.y * 128, n0 = blockIdx.x * 128;
  const int ar = tid >> 1, ak = (tid & 1) * 8;
  const int br = tid >> 4, bc = (tid & 15) * 8;
  float acc[8][8] = {};
  float4 ra0, ra1, rb0, rb1;
  ra0 = *(const float4*)&A[(size_t)(m0 + ar) * K + ak];
  ra1 = *(const float4*)&A[(size_t)(m0 + ar) * K + ak + 4];
  rb0 = *(const float4*)&B[(size_t)br * N + n0 + bc];
  rb1 = *(const float4*)&B[(size_t)br * N + n0 + bc + 4];
  for (int k0 = 0; k0 < K; k0 += 16) {
    As[ak + 0][ar] = ra0.x; As[ak + 1][ar] = ra0.y;
    As[ak + 2][ar] = ra0.z; As[ak + 3][ar] = ra0.w;
    As[ak + 4][ar] = ra1.x; As[ak + 5][ar] = ra1.y;
    As[ak + 6][ar] = ra1.z; As[ak + 7][ar] = ra1.w;
    *(float4*)&Bs[br][bc]     = rb0;
    *(float4*)&Bs[br][bc + 4] = rb1;
    __syncthreads();
    if (k0 + 16 < K) {
      ra0 = *(const float4*)&A[(size_t)(m0 + ar) * K + k0 + 16 + ak];
      ra1 = *(const float4*)&A[(size_t)(m0 + ar) * K + k0 + 16 + ak + 4];
      rb0 = *(const float4*)&B[(size_t)(k0 + 16 + br) * N + n0 + bc];
      rb1 = *(const float4*)&B[(size_t)(k0 + 16 + br) * N + n0 + bc + 4];
    }
#pragma unroll
    for (int kk = 0; kk < 16; ++kk) {
      float4 aA = *(const float4*)&As[kk][ty * 8];
      float4 aB = *(const float4*)&As[kk][ty * 8 + 4];
      float4 bA = *(const float4*)&Bs[kk][tx * 8];
      float4 bB = *(const float4*)&Bs[kk][tx * 8 + 4];
      float a[8] = {aA.x, aA.y, aA.z, aA.w, aB.x, aB.y, aB.z, aB.w};
      float b[8] = {bA.x, bA.y, bA.z, bA.w, bB.x, bB.y, bB.z, bB.w};
#pragma unroll
      for (int i = 0; i < 8; ++i)
#pragma unroll
        for (int j = 0; j < 8; ++j) acc[i][j] += a[i] * b[j];
    }
    __syncthreads();
  }
#pragma unroll
  for (int i = 0; i < 8; ++i) {
    size_t off = (size_t)(m0 + ty * 8 + i) * N + n0 + tx * 8;
    float4 o0 = {acc[i][0], acc[i][1], acc[i][2], acc[i][3]};
    float4 o1 = {acc[i][4], acc[i][5], acc[i][6], acc[i][7]};
    if (Cadd) {
      float4 c0 = *(const float4*)&Cadd[off];
      float4 c1 = *(const float4*)&Cadd[off + 4];
      o0.x += c0.x; o0.y += c0.y; o0.z += c0.z; o0.w += c0.w;
      o1.x += c1.x; o1.y += c1.y; o1.z += c1.z; o1.w += c1.w;
    }
    *(float4*)&C[off] = o0;
    *(float4*)&C[off + 4] = o1;
  }
}

// ---------------- ba = x1 @ W_ba  (N=16)
__global__ __launch_bounds__(256) void k_ba(const float* __restrict__ x1,
                                            const float* __restrict__ Wba,
                                            float* __restrict__ ba) {
  const int t = blockIdx.x, tid = threadIdx.x;
  const int n = tid >> 4, kl = tid & 15;
  const float* xr = x1 + (size_t)t * HID;
  float s = 0.f;
  for (int k = kl; k < HID; k += 16) s += xr[k] * Wba[k * 16 + n];
  for (int m = 1; m < 16; m <<= 1) s += __shfl_xor(s, m);
  if (kl == 0) ba[t * 16 + n] = s;
}

// ---------------- beta = sigmoid(b); g = -exp(A_log)*softplus(a+dt_bias)
__global__ __launch_bounds__(256) void k_bg(const float* __restrict__ ba,
                                            const float* __restrict__ dt_bias,
                                            const float* __restrict__ A_log,
                                            float* __restrict__ gb,
                                            float* __restrict__ beta) {
  int i = blockIdx.x * 256 + threadIdx.x;
  if (i >= S * HV) return;
  int t = i >> 3, h = i & 7;
  float b = ba[t * 16 + h];
  float a = ba[t * 16 + 8 + h];
  beta[i] = 1.f / (1.f + expf(-b));
  float x = a + dt_bias[h];
  float sp = fmaxf(x, 0.f) + log1pf(expf(-fabsf(x)));
  gb[i] = -expf(A_log[h]) * sp;
}

// ---------------- causal depthwise conv (K=4) + silu on qkvz cols [0,2048)
__global__ __launch_bounds__(256) void k_conv(const float* __restrict__ qkvz,
                                              const float* __restrict__ cw,
                                              float* __restrict__ conv) {
  int idx = blockIdx.x * 256 + threadIdx.x;
  int t = idx >> 11, c = idx & 2047;
  float4 w = ((const float4*)cw)[c];
  float acc = 0.f;
  if (t >= 3) {
    acc = qkvz[(size_t)(t - 3) * QKVZ_N + c] * w.x
        + qkvz[(size_t)(t - 2) * QKVZ_N + c] * w.y
        + qkvz[(size_t)(t - 1) * QKVZ_N + c] * w.z
        + qkvz[(size_t)(t    ) * QKVZ_N + c] * w.w;
  } else {
    if (t - 3 >= 0) acc += qkvz[(size_t)(t - 3) * QKVZ_N + c] * w.x;
    if (t - 2 >= 0) acc += qkvz[(size_t)(t - 2) * QKVZ_N + c] * w.y;
    if (t - 1 >= 0) acc += qkvz[(size_t)(t - 1) * QKVZ_N + c] * w.z;
    acc += qkvz[(size_t)t * QKVZ_N + c] * w.w;
  }
  conv[idx] = acc / (1.f + expf(-acc));
}

// ---------------- l2-normalize q,k per source head; repeat to 8 dest heads
__global__ __launch_bounds__(512) void k_prep(const float* __restrict__ conv,
                                              float* __restrict__ qn,
                                              float* __restrict__ kn) {
  const int t = blockIdx.x, tid = threadIdx.x;
  const int sh = tid >> 7;
  const int d = tid & 127;
  float qv = conv[(size_t)t * CONV_DIM + sh * DK + d];
  float kv = conv[(size_t)t * CONV_DIM + KEY_DIM + sh * DK + d];
  float sq = qv * qv, sk = kv * kv;
  for (int m = 1; m < 64; m <<= 1) { sq += __shfl_xor(sq, m); sk += __shfl_xor(sk, m); }
  __shared__ float rq[8], rk[8];
  const int wave = tid >> 6;
  if ((tid & 63) == 0) { rq[wave] = sq; rk[wave] = sk; }
  __syncthreads();
  float sumq = rq[sh * 2] + rq[sh * 2 + 1];
  float sumk = rk[sh * 2] + rk[sh * 2 + 1];
  float qs = (1.f / sqrtf(sumq + EPS)) * 0.08838834764831845f;
  float ks = 1.f / sqrtf(sumk + EPS);
  float qo = qv * qs, ko = kv * ks;
  size_t b0 = (size_t)t * 1024 + (size_t)(sh * 2) * DK + d;
  qn[b0] = qo; qn[b0 + DK] = qo;
  kn[b0] = ko; kn[b0 + DK] = ko;
}

// ================= chunked gated delta rule =================
__global__ __launch_bounds__(256) void k_chunkA(
    const float* __restrict__ qn, const float* __restrict__ kn,
    const float* __restrict__ conv, const float* __restrict__ gbuf,
    const float* __restrict__ betab,
    float* __restrict__ Upre, float* __restrict__ WpT,
    float* __restrict__ Qdt, float* __restrict__ Kdm,
    float* __restrict__ BqT, float* __restrict__ dec) {
  const int h = blockIdx.x >> 5;
  const int ch = blockIdx.x & 31;
  const int tid = threadIdx.x;
  const int t_base = ch * CK;

  __shared__ float KT[128][68];
  __shared__ float UB[8704];
  __shared__ float Am[64][68];
  __shared__ float Mm[64][68];
  __shared__ float c_l[64], b_l[64], sW[64], seQ[64], sKd[64];

#pragma unroll
  for (int i = 0; i < 8; ++i) {
    int w = (i * 256 + tid) * 4;
    int tt = w >> 7, r = w & 127;
    float4 v = *(const float4*)&kn[(size_t)(t_base + tt) * 1024 + h * 128 + r];
    KT[r + 0][tt] = v.x; KT[r + 1][tt] = v.y; KT[r + 2][tt] = v.z; KT[r + 3][tt] = v.w;
  }
  if (tid < 64) {
    c_l[tid] = gbuf[(t_base + tid) * HV + h];
    b_l[tid] = betab[(t_base + tid) * HV + h];
  }
  __syncthreads();
  if (tid == 0) {
    float run = 0.f;
    for (int t = 0; t < 64; ++t) { run += c_l[t]; c_l[t] = run; }
    dec[h * NC + ch] = expf(run);
  }
  __syncthreads();
  if (tid < 64) {
    sW[tid] = b_l[tid] * expf(c_l[tid]);
    seQ[tid] = expf(c_l[tid]);
    sKd[tid] = expf(c_l[63] - c_l[tid]);
  }
  __syncthreads();

  {
    const int t0 = (tid >> 4) * 4, j0 = (tid & 15) * 4;
    float acc[4][4] = {};
    for (int r = 0; r < 128; ++r) {
      float4 a = *(const float4*)&KT[r][t0];
      float4 b = *(const float4*)&KT[r][j0];
      float av[4] = {a.x, a.y, a.z, a.w};
      float bv[4] = {b.x, b.y, b.z, b.w};
#pragma unroll
      for (int i = 0; i < 4; ++i)
#pragma unroll
        for (int j = 0; j < 4; ++j) acc[i][j] += av[i] * bv[j];
    }
#pragma unroll
    for (int i = 0; i < 4; ++i)
#pragma unroll
      for (int j = 0; j < 4; ++j) {
        int t = t0 + i, jj = j0 + j;
        Am[t][jj] = (jj < t) ? b_l[t] * expf(c_l[t] - c_l[jj]) * acc[i][j] : 0.f;
      }
  }
  __syncthreads();

  if (tid < 64) {
    const int c = tid;
    Mm[0][c] = (c == 0) ? 1.f : 0.f;
    for (int t = 1; t < 64; ++t) {
      float a = (c == t) ? 1.f : 0.f;
      for (int j = 0; j < t; ++j) a -= Am[t][j] * Mm[j][c];
      Mm[t][c] = a;
    }
  }
  __syncthreads();

  float* Vsm = UB;
#pragma unroll
  for (int i = 0; i < 8; ++i) {
    int w = (i * 256 + tid) * 4;
    int j = w >> 7, cc = w & 127;
    float4 v = *(const float4*)&conv[(size_t)(t_base + j) * CONV_DIM + 1024 + h * 128 + cc];
    float bj = b_l[j];
    v.x *= bj; v.y *= bj; v.z *= bj; v.w *= bj;
    *(float4*)&Vsm[j * 132 + cc] = v;
  }
  __syncthreads();

  const size_t cb = (size_t)h * NC + ch;
  {
    const int t0 = (tid >> 4) * 4, c0 = (tid & 15) * 8;
    float acc[4][8] = {};
    for (int j = 0; j < 64; ++j) {
      float m[4];
#pragma unroll
      for (int i = 0; i < 4; ++i) m[i] = Mm[t0 + i][j];
      float4 va = *(const float4*)&Vsm[j * 132 + c0];
      float4 vb = *(const float4*)&Vsm[j * 132 + c0 + 4];
      float v[8] = {va.x, va.y, va.z, va.w, vb.x, vb.y, vb.z, vb.w};
#pragma unroll
      for (int i = 0; i < 4; ++i)
#pragma unroll
        for (int c = 0; c < 8; ++c) acc[i][c] += m[i] * v[c];
    }
#pragma unroll
    for (int i = 0; i < 4; ++i) {
      float4 o0 = {acc[i][0], acc[i][1], acc[i][2], acc[i][3]};
      float4 o1 = {acc[i][4], acc[i][5], acc[i][6], acc[i][7]};
      *(float4*)&Upre[cb * 8192 + (size_t)(t0 + i) * 128 + c0] = o0;
      *(float4*)&Upre[cb * 8192 + (size_t)(t0 + i) * 128 + c0 + 4] = o1;
    }
  }
  {
    const int r0 = (tid >> 3) * 4, t0 = (tid & 7) * 8;
    float acc[4][8] = {};
    for (int j = 0; j < 64; ++j) {
      float s = sW[j];
      float kk[4];
#pragma unroll
      for (int i = 0; i < 4; ++i) kk[i] = KT[r0 + i][j] * s;
      float m[8];
#pragma unroll
      for (int t = 0; t < 8; ++t) m[t] = Mm[t0 + t][j];
#pragma unroll
      for (int i = 0; i < 4; ++i)
#pragma unroll
        for (int t = 0; t < 8; ++t) acc[i][t] += kk[i] * m[t];
    }
#pragma unroll
    for (int i = 0; i < 4; ++i) {
      float4 o0 = {acc[i][0], acc[i][1], acc[i][2], acc[i][3]};
      float4 o1 = {acc[i][4], acc[i][5], acc[i][6], acc[i][7]};
      *(float4*)&WpT[cb * 8192 + (size_t)(r0 + i) * 64 + t0] = o0;
      *(float4*)&WpT[cb * 8192 + (size_t)(r0 + i) * 64 + t0 + 4] = o1;
    }
  }
  __syncthreads();

  float* QT = UB;
#pragma unroll
  for (int i = 0; i < 8; ++i) {
    int w = (i * 256 + tid) * 4;
    int tt = w >> 7, r = w & 127;
    float4 v = *(const float4*)&qn[(size_t)(t_base + tt) * 1024 + h * 128 + r];
    QT[(r + 0) * 68 + tt] = v.x; QT[(r + 1) * 68 + tt] = v.y;
    QT[(r + 2) * 68 + tt] = v.z; QT[(r + 3) * 68 + tt] = v.w;
  }
  __syncthreads();

  {
    const int t0 = (tid >> 4) * 4, j0 = (tid & 15) * 4;
    float acc[4][4] = {};
    for (int r = 0; r < 128; ++r) {
      float4 a = *(const float4*)&QT[r * 68 + t0];
      float4 b = *(const float4*)&KT[r][j0];
      float av[4] = {a.x, a.y, a.z, a.w};
      float bv[4] = {b.x, b.y, b.z, b.w};
#pragma unroll
      for (int i = 0; i < 4; ++i)
#pragma unroll
        for (int j = 0; j < 4; ++j) acc[i][j] += av[i] * bv[j];
    }
#pragma unroll
    for (int i = 0; i < 4; ++i)
#pragma unroll
      for (int j = 0; j < 4; ++j) {
        int t = t0 + i, jj = j0 + j;
        BqT[cb * 4096 + (size_t)jj * 64 + t] =
            (jj <= t) ? expf(c_l[t] - c_l[jj]) * acc[i][j] : 0.f;
      }
  }
#pragma unroll
  for (int i = 0; i < 8; ++i) {
    int w = (i * 256 + tid) * 4;
    int r = w >> 6, t = w & 63;
    float4 q = *(const float4*)&QT[r * 68 + t];
    float4 s = *(const float4*)&seQ[t];
    q.x *= s.x; q.y *= s.y; q.z *= s.z; q.w *= s.w;
    *(float4*)&Qdt[cb * 8192 + w] = q;
  }
#pragma unroll
  for (int i = 0; i < 8; ++i) {
    int w = (i * 256 + tid) * 4;
    int t = w >> 7, r = w & 127;
    float s = sKd[t];
    float4 o;
    o.x = KT[r + 0][t] * s; o.y = KT[r + 1][t] * s;
    o.z = KT[r + 2][t] * s; o.w = KT[r + 3][t] * s;
    *(float4*)&Kdm[cb * 8192 + w] = o;
  }
}

// Sequential state kernel: 64 blocks = 8 heads x 8 col-groups (16 cols).
// Per chunk: store S_start, u = Upre - W^T S, S = dC*S + Kd^T u.
// Next-chunk Wp/Kd prefetched into registers during compute.
__global__ __launch_bounds__(256) void k_chunkS(
    const float* __restrict__ Upre, const float* __restrict__ WpT,
    const float* __restrict__ Kdm, const float* __restrict__ dec,
    float* __restrict__ Schk0, float* __restrict__ Schk1) {
  const int h = blockIdx.x >> 3;
  const int cg = blockIdx.x & 7;
  const int cbase = cg * 16;
  const int tid = threadIdx.x;

  __shared__ float Sm[128][20];
  __shared__ float um[64][20];
  __shared__ float bufW[128 * 68];
  __shared__ float bufK[64 * 132];

  for (int i = tid; i < 128 * 20; i += 256) (&Sm[0][0])[i] = 0.f;

  float* Sc_base = (h < 4) ? (Schk0 + (size_t)(h * 8 + cg) * NC * 2048)
                           : (Schk1 + (size_t)((h - 4) * 8 + cg) * NC * 2048);

  const int t0 = (tid >> 3) * 2;
  const int cc = (tid & 7) * 2;
  const int r0 = (tid >> 3) * 4;
  const int sr = tid >> 1, sc = (tid & 1) * 8;

  float4 pw[8], pk[8];
  {
    const float* Wp = WpT + (size_t)h * NC * 8192;
    const float* Kp = Kdm + (size_t)h * NC * 8192;
#pragma unroll
    for (int i = 0; i < 8; ++i) {
      int w = (i * 256 + tid) * 4;
      pw[i] = *(const float4*)&Wp[w];
      pk[i] = *(const float4*)&Kp[w];
    }
  }
  __syncthreads();

  for (int ch = 0; ch < NC; ++ch) {
    const size_t cb = (size_t)h * NC + ch;
    const float* Up = Upre + cb * 8192;
    const float dC = dec[cb];

    // staged regs -> LDS
#pragma unroll
    for (int i = 0; i < 8; ++i) {
      int w = (i * 256 + tid) * 4;
      *(float4*)&bufW[(w >> 6) * 68 + (w & 63)] = pw[i];
      *(float4*)&bufK[(w >> 7) * 132 + (w & 127)] = pk[i];
    }
    __syncthreads();

    // issue next-chunk prefetch (hidden under compute)
    if (ch + 1 < NC) {
      const float* Wp = WpT + (cb + 1) * 8192;
      const float* Kp = Kdm + (cb + 1) * 8192;
#pragma unroll
      for (int i = 0; i < 8; ++i) {
        int w = (i * 256 + tid) * 4;
        pw[i] = *(const float4*)&Wp[w];
        pk[i] = *(const float4*)&Kp[w];
      }
    }

    // store S_start (before update)
    {
      float* Sc = Sc_base + (size_t)ch * 2048;
      float4 s0 = *(const float4*)&Sm[sr][sc];
      float4 s1 = *(const float4*)&Sm[sr][sc + 4];
      *(float4*)&Sc[tid * 8] = s0;
      *(float4*)&Sc[tid * 8 + 4] = s1;
    }

    // u[t][c] = Up[t][c] - sum_r W[r][t]*S[r][c]
    {
      float a00 = 0, a01 = 0, a10 = 0, a11 = 0;
#pragma unroll 4
      for (int r = 0; r < 128; ++r) {
        float2 wv = *(const float2*)&bufW[r * 68 + t0];
        float2 sv = *(const float2*)&Sm[r][cc];
        a00 += wv.x * sv.x; a01 += wv.x * sv.y;
        a10 += wv.y * sv.x; a11 += wv.y * sv.y;
      }
      float2 u0 = *(const float2*)&Up[(size_t)t0 * 128 + cbase + cc];
      float2 u1 = *(const float2*)&Up[(size_t)(t0 + 1) * 128 + cbase + cc];
      u0.x -= a00; u0.y -= a01;
      u1.x -= a10; u1.y -= a11;
      *(float2*)&um[t0][cc] = u0;
      *(float2*)&um[t0 + 1][cc] = u1;
    }
    __syncthreads();

    // S[r][c] = dC*S[r][c] + sum_t Kd[t][r]*u[t][c]
    {
      float acc[4][2] = {};
#pragma unroll 2
      for (int t = 0; t < 64; ++t) {
        float4 kv = *(const float4*)&bufK[t * 132 + r0];
        float2 uv = *(const float2*)&um[t][cc];
        acc[0][0] += kv.x * uv.x; acc[0][1] += kv.x * uv.y;
        acc[1][0] += kv.y * uv.x; acc[1][1] += kv.y * uv.y;
        acc[2][0] += kv.z * uv.x; acc[2][1] += kv.z * uv.y;
        acc[3][0] += kv.w * uv.x; acc[3][1] += kv.w * uv.y;
      }
#pragma unroll
      for (int i = 0; i < 4; ++i) {
        float2 s = *(const float2*)&Sm[r0 + i][cc];
        s.x = dC * s.x + acc[i][0];
        s.y = dC * s.y + acc[i][1];
        *(float2*)&Sm[r0 + i][cc] = s;
      }
    }
    __syncthreads();
  }
}

// Parallel output kernel: grid (cg 8, ch 32, h 8).
// u = Upre - W^T S_start; O = Qd^T S_start + Bq^T u.
__global__ __launch_bounds__(256) void k_chunkO(
    const float* __restrict__ Upre, const float* __restrict__ WpT,
    const float* __restrict__ Qdt, const float* __restrict__ BqT,
    const float* __restrict__ Schk0, const float* __restrict__ Schk1,
    float* __restrict__ core) {
  const int cg = blockIdx.x;
  const int ch = blockIdx.y;
  const int h = blockIdx.z;
  const int cbase = cg * 16;
  const int tid = threadIdx.x;

  __shared__ float Sm[128][20];
  __shared__ float um[64][20];
  __shared__ float buf[128 * 68];
  __shared__ float Bs[64][68];

  const size_t cb = (size_t)h * NC + ch;
  const float* Up = Upre + cb * 8192;
  const float* Sc = ((h < 4) ? (Schk0 + (size_t)(h * 8 + cg) * NC * 2048)
                             : (Schk1 + (size_t)((h - 4) * 8 + cg) * NC * 2048))
                    + (size_t)ch * 2048;

  // load S_start
  {
    const int sr = tid >> 1, sc2 = (tid & 1) * 8;
    float4 s0 = *(const float4*)&Sc[tid * 8];
    float4 s1 = *(const float4*)&Sc[tid * 8 + 4];
    *(float4*)&Sm[sr][sc2] = s0;
    *(float4*)&Sm[sr][sc2 + 4] = s1;
  }
  // stage Wp, Bq
  {
    const float* Wp = WpT + cb * 8192;
    const float* Bp = BqT + cb * 4096;
#pragma unroll
    for (int i = 0; i < 8; ++i) {
      int w = (i * 256 + tid) * 4;
      *(float4*)&buf[(w >> 6) * 68 + (w & 63)] = *(const float4*)&Wp[w];
    }
#pragma unroll
    for (int i = 0; i < 4; ++i) {
      int w = (i * 256 + tid) * 4;
      *(float4*)&Bs[w >> 6][w & 63] = *(const float4*)&Bp[w];
    }
  }
  __syncthreads();

  const int t0 = (tid >> 3) * 2;
  const int cc = (tid & 7) * 2;

  // u
  {
    float a00 = 0, a01 = 0, a10 = 0, a11 = 0;
#pragma unroll 4
    for (int r = 0; r < 128; ++r) {
      float2 wv = *(const float2*)&buf[r * 68 + t0];
      float2 sv = *(const float2*)&Sm[r][cc];
      a00 += wv.x * sv.x; a01 += wv.x * sv.y;
      a10 += wv.y * sv.x; a11 += wv.y * sv.y;
    }
    float2 u0 = *(const float2*)&Up[(size_t)t0 * 128 + cbase + cc];
    float2 u1 = *(const float2*)&Up[(size_t)(t0 + 1) * 128 + cbase + cc];
    u0.x -= a00; u0.y -= a01;
    u1.x -= a10; u1.y -= a11;
    *(float2*)&um[t0][cc] = u0;
    *(float2*)&um[t0 + 1][cc] = u1;
  }
  __syncthreads();

  // stage Qd (overwrites Wp in buf)
  {
    const float* Qp = Qdt + cb * 8192;
#pragma unroll
    for (int i = 0; i < 8; ++i) {
      int w = (i * 256 + tid) * 4;
      *(float4*)&buf[(w >> 6) * 68 + (w & 63)] = *(const float4*)&Qp[w];
    }
  }
  __syncthreads();

  // O
  {
    float a00 = 0, a01 = 0, a10 = 0, a11 = 0;
#pragma unroll 4
    for (int r = 0; r < 128; ++r) {
      float2 qv = *(const float2*)&buf[r * 68 + t0];
      float2 sv = *(const float2*)&Sm[r][cc];
      a00 += qv.x * sv.x; a01 += qv.x * sv.y;
      a10 += qv.y * sv.x; a11 += qv.y * sv.y;
    }
#pragma unroll 4
    for (int j = 0; j < 64; ++j) {
      float2 bv = *(const float2*)&Bs[j][t0];
      float2 uv = *(const float2*)&um[j][cc];
      a00 += bv.x * uv.x; a01 += bv.x * uv.y;
      a10 += bv.y * uv.x; a11 += bv.y * uv.y;
    }
    float2 o0 = {a00, a01}, o1 = {a10, a11};
    *(float2*)&core[(size_t)(ch * 64 + t0) * 1024 + h * 128 + cbase + cc] = o0;
    *(float2*)&core[(size_t)(ch * 64 + t0 + 1) * 1024 + h * 128 + cbase + cc] = o1;
  }
}

// ---------------- gated RMSNorm per value head * silu(z); in-place safe (f32)
__global__ __launch_bounds__(256) void k_gatenorm(const float* __restrict__ core,
                                                  const float* __restrict__ qkvz,
                                                  const float* __restrict__ gnw,
                                                  float* __restrict__ y) {
  const int t = blockIdx.x, tid = threadIdx.x;
  const int wave = tid >> 6, lane = tid & 63;
  const int h = blockIdx.y * 4 + wave;
  const float* cbp = core + (size_t)t * 1024 + h * DV;
  float c0 = cbp[lane], c1 = cbp[lane + 64];
  float ss = c0 * c0 + c1 * c1;
  for (int m = 1; m < 64; m <<= 1) ss += __shfl_xor(ss, m);
  float scale = 1.f / sqrtf(ss * (1.0f / DV) + EPS);
  const float* zb = qkvz + (size_t)t * QKVZ_N + 2 * KEY_DIM + VAL_DIM + h * DV;
  float z0 = zb[lane], z1 = zb[lane + 64];
  float g0 = gnw[lane], g1 = gnw[lane + 64];
  float o0 = c0 * scale * g0 * (z0 / (1.f + expf(-z0)));
  float o1 = c1 * scale * g1 * (z1 / (1.f + expf(-z1)));
  float* yb = y + (size_t)t * 1024 + h * DV;
  yb[lane] = o0; yb[lane + 64] = o1;
}

// ---------------- router
__global__ __launch_bounds__(256) void k_router(const float* __restrict__ x2,
                                                const float* __restrict__ Wr,
                                                float* __restrict__ rinfo,
                                                int* __restrict__ cnt,
                                                float* __restrict__ outTopi) {
  const int t = blockIdx.x, tid = threadIdx.x;
  const int n = tid >> 5, kl = tid & 31;
  const float* xr = x2 + (size_t)t * HID;
  float s = 0.f;
  for (int k = kl; k < HID; k += 32) s += xr[k] * Wr[k * 8 + n];
  for (int m = 1; m < 32; m <<= 1) s += __shfl_xor(s, m);
  __shared__ float lg[8];
  if (kl == 0) lg[n] = s;
  __syncthreads();
  if (tid == 0) {
    int i0 = 0; float m0 = lg[0];
    for (int e = 1; e < 8; ++e) if (lg[e] > m0) { m0 = lg[e]; i0 = e; }
    int i1 = -1; float m1 = -1e30f;
    for (int e = 0; e < 8; ++e) if (e != i0 && lg[e] > m1) { m1 = lg[e]; i1 = e; }
    float e1 = expf(m1 - m0);
    float w0 = 1.f / (1.f + e1);
    float w1 = e1 / (1.f + e1);
    rinfo[t * 4 + 0] = (float)i0; rinfo[t * 4 + 1] = (float)i1;
    rinfo[t * 4 + 2] = w0;        rinfo[t * 4 + 3] = w1;
    atomicAdd(&cnt[i0], 1);
    atomicAdd(&cnt[i1], 1);
    outTopi[t * 2 + 0] = (float)i0;
    outTopi[t * 2 + 1] = (float)i1;
  }
}

__global__ void k_offsets(const int* __restrict__ cnt, int* __restrict__ offs,
                          int* __restrict__ cnt2) {
  if (threadIdx.x == 0) {
    int a = 0;
    for (int e = 0; e < 8; ++e) { offs[e] = a; a += cnt[e]; cnt2[e] = 0; }
  }
}

__global__ __launch_bounds__(256) void k_scatter(const float* __restrict__ rinfo,
                                                 const int* __restrict__ offs,
                                                 int* __restrict__ cnt2,
                                                 int* __restrict__ pairTok,
                                                 int* __restrict__ tokPos) {
  int t = blockIdx.x * 256 + threadIdx.x;
  if (t >= S) return;
  int i0 = (int)rinfo[t * 4 + 0], i1 = (int)rinfo[t * 4 + 1];
  int p0 = offs[i0] + atomicAdd(&cnt2[i0], 1);
  pairTok[p0] = t;
  int p1 = offs[i1] + atomicAdd(&cnt2[i1], 1);
  pairTok[p1] = t;
  tokPos[t * 2 + 0] = p0;
  tokPos[t * 2 + 1] = p1;
}

// ---------------- MoE stage 1 (MFMA bf16)
__global__ __launch_bounds__(256) void k_moe1m(const u16* __restrict__ x2b,
                                               const u16* __restrict__ WgT,
                                               const u16* __restrict__ WuT,
                                               const int* __restrict__ offs,
                                               const int* __restrict__ cnt,
                                               const int* __restrict__ pairTok,
                                               u16* __restrict__ act) {
  const int e = blockIdx.z;
  const int count = cnt[e];
  const int m0 = blockIdx.y * 128;
  if (m0 >= count) return;
  const int base = offs[e];
  __shared__ u16 Abuf[4096], Gbuf[4096], Ubuf[4096];
  const int tid = threadIdx.x;
  const int lane = tid & 63, wave = tid >> 6;
  const int wm = wave >> 1, wn = wave & 1;
  const int n0 = blockIdx.x * 128;
  const int wb0 = wave * 512, wb1 = 2048 + wave * 512;
  const int r0 = tid >> 2;
  int mr0 = m0 + r0;       if (mr0 > count - 1) mr0 = count - 1;
  int mr1 = m0 + r0 + 64;  if (mr1 > count - 1) mr1 = count - 1;
  const int t0tok = pairTok[base + mr0];
  const int t1tok = pairTok[base + mr1];
  const u16* Ag0 = x2b + (size_t)t0tok * 1024 + (tid & 3) * 8;
  const u16* Ag1 = x2b + (size_t)t1tok * 1024 + (tid & 3) * 8;
  const u16* Gg0 = WgT + (size_t)e * 512 * 1024 + (size_t)(n0 + r0) * 1024 + (tid & 3) * 8;
  const u16* Gg1 = Gg0 + (size_t)64 * 1024;
  const u16* Ug0 = WuT + (size_t)e * 512 * 1024 + (size_t)(n0 + r0) * 1024 + (tid & 3) * 8;
  const u16* Ug1 = Ug0 + (size_t)64 * 1024;
  f32x4 ag[4][4] = {}, au[4][4] = {};
  const int fr = lane & 15, kg = lane >> 4;
  for (int k0 = 0; k0 < 1024; k0 += 32) {
    gload16(Ag0 + k0, Abuf + wb0);
    gload16(Ag1 + k0, Abuf + wb1);
    gload16(Gg0 + k0, Gbuf + wb0);
    gload16(Gg1 + k0, Gbuf + wb1);
    gload16(Ug0 + k0, Ubuf + wb0);
    gload16(Ug1 + k0, Ubuf + wb1);
    __syncthreads();
    bf16x8 af[4], gf[4], uf[4];
#pragma unroll
    for (int i = 0; i < 4; ++i) {
      af[i] = *(const bf16x8*)&Abuf[(wm * 64 + i * 16 + fr) * 32 + kg * 8];
      gf[i] = *(const bf16x8*)&Gbuf[(wn * 64 + i * 16 + fr) * 32 + kg * 8];
      uf[i] = *(const bf16x8*)&Ubuf[(wn * 64 + i * 16 + fr) * 32 + kg * 8];
    }
#pragma unroll
    for (int i = 0; i < 4; ++i)
#pragma unroll
      for (int j = 0; j < 4; ++j) {
        ag[i][j] = __builtin_amdgcn_mfma_f32_16x16x32_bf16(af[i], gf[j], ag[i][j], 0, 0, 0);
        au[i][j] = __builtin_amdgcn_mfma_f32_16x16x32_bf16(af[i], uf[j], au[i][j], 0, 0, 0);
      }
    __syncthreads();
  }
#pragma unroll
  for (int i = 0; i < 4; ++i) {
#pragma unroll
    for (int j = 0; j < 4; ++j) {
      int rowt = wm * 64 + i * 16 + kg * 4;
      int col = n0 + wn * 64 + j * 16 + fr;
#pragma unroll
      for (int r = 0; r < 4; ++r) {
        if (m0 + rowt + r < count) {
          float g = ag[i][j][r], u = au[i][j][r];
          act[(size_t)(base + m0 + rowt + r) * 512 + col] =
              f2b(g / (1.f + expf(-g)) * u);
        }
      }
    }
  }
}

// ---------------- MoE stage 2 (MFMA bf16): eo = act @ Wd[e]
__global__ __launch_bounds__(256) void k_moe2m(const u16* __restrict__ act,
                                               const u16* __restrict__ WdT,
                                               const int* __restrict__ offs,
                                               const int* __restrict__ cnt,
                                               float* __restrict__ eo) {
  const int e = blockIdx.z;
  const int count = cnt[e];
  const int m0 = blockIdx.y * 128;
  if (m0 >= count) return;
  const int base = offs[e];
  __shared__ u16 Abuf[4096], Bbuf[4096];
  const int tid = threadIdx.x;
  const int lane = tid & 63, wave = tid >> 6;
  const int wm = wave >> 1, wn = wave & 1;
  const int n0 = blockIdx.x * 128;
  const int wb0 = wave * 512, wb1 = 2048 + wave * 512;
  const int r0 = tid >> 2;
  int mr0 = m0 + r0;       if (mr0 > count - 1) mr0 = count - 1;
  int mr1 = m0 + r0 + 64;  if (mr1 > count - 1) mr1 = count - 1;
  const u16* Ag0 = act + (size_t)(base + mr0) * 512 + (tid & 3) * 8;
  const u16* Ag1 = act + (size_t)(base + mr1) * 512 + (tid & 3) * 8;
  const u16* Bg0 = WdT + (size_t)e * 1024 * 512 + (size_t)(n0 + r0) * 512 + (tid & 3) * 8;
  const u16* Bg1 = Bg0 + (size_t)64 * 512;
  f32x4 acc[4][4] = {};
  const int fr = lane & 15, kg = lane >> 4;
  for (int k0 = 0; k0 < 512; k0 += 32) {
    gload16(Ag0 + k0, Abuf + wb0);
    gload16(Ag1 + k0, Abuf + wb1);
    gload16(Bg0 + k0, Bbuf + wb0);
    gload16(Bg1 + k0, Bbuf + wb1);
    __syncthreads();
    bf16x8 af[4], bfr[4];
#pragma unroll
    for (int i = 0; i < 4; ++i) {
      af[i]  = *(const bf16x8*)&Abuf[(wm * 64 + i * 16 + fr) * 32 + kg * 8];
      bfr[i] = *(const bf16x8*)&Bbuf[(wn * 64 + i * 16 + fr) * 32 + kg * 8];
    }
#pragma unroll
    for (int i = 0; i < 4; ++i)
#pragma unroll
      for (int j = 0; j < 4; ++j)
        acc[i][j] = __builtin_amdgcn_mfma_f32_16x16x32_bf16(af[i], bfr[j], acc[i][j], 0, 0, 0);
    __syncthreads();
  }
#pragma unroll
  for (int i = 0; i < 4; ++i) {
#pragma unroll
    for (int j = 0; j < 4; ++j) {
      int rowt = wm * 64 + i * 16 + kg * 4;
      int col = n0 + wn * 64 + j * 16 + fr;
#pragma unroll
      for (int r = 0; r < 4; ++r) {
        if (m0 + rowt + r < count)
          eo[(size_t)(base + m0 + rowt + r) * 1024 + col] = acc[i][j][r];
      }
    }
  }
}

// ---------------- final: out[t] += w0*eo[p0] + w1*eo[p1]
__global__ __launch_bounds__(256) void k_finish(const float* __restrict__ eo,
                                                const int* __restrict__ tokPos,
                                                const float* __restrict__ rinfo,
                                                float* __restrict__ out) {
  const int t = blockIdx.x;
  const int c = threadIdx.x * 4;
  float w0 = rinfo[t * 4 + 2], w1 = rinfo[t * 4 + 3];
  int p0 = tokPos[t * 2 + 0], p1 = tokPos[t * 2 + 1];
  float4 a = *(const float4*)&eo[(size_t)p0 * 1024 + c];
  float4 b = *(const float4*)&eo[(size_t)p1 * 1024 + c];
  float4 o = *(const float4*)&out[(size_t)t * 1024 + c];
  o.x += w0 * a.x + w1 * b.x;
  o.y += w0 * a.y + w1 * b.y;
  o.z += w0 * a.z + w1 * b.z;
  o.w += w0 * a.w + w1 * b.w;
  *(float4*)&out[(size_t)t * 1024 + c] = o;
}

extern "C" void kernel_launch(void* const* d_in, const int* in_sizes, int n_in,
                              void* d_out, int out_size, void* d_ws, size_t ws_size,
                              hipStream_t stream) {
  const float* hid      = (const float*)d_in[0];
  const float* w_ln1    = (const float*)d_in[1];
  const float* w_ln2    = (const float*)d_in[2];
  const float* W_qkvz   = (const float*)d_in[3];
  const float* W_ba     = (const float*)d_in[4];
  const float* conv_w   = (const float*)d_in[5];
  const float* dt_bias  = (const float*)d_in[6];
  const float* A_log    = (const float*)d_in[7];
  const float* gnw      = (const float*)d_in[8];
  const float* W_out    = (const float*)d_in[9];
  const float* W_router = (const float*)d_in[10];
  const float* W_gate   = (const float*)d_in[11];
  const float* W_up     = (const float*)d_in[12];
  const float* W_down   = (const float*)d_in[13];

  float* ws = (float*)d_ws;
  const size_t M1 = (size_t)1024 * 1024;
  float* x1    = ws;               // 2M f32 (x2 later; Schk0 during scan)
  float* qkvz  = x1 + 2 * M1;      // 6M
  float* conv  = qkvz + 6 * M1;    // 4M (WgT/WuT after chunkA)
  float* qn    = conv + 4 * M1;    // 2M (Schk1 during scan)
  float* kn    = qn + 2 * M1;      // 2M (WdT after chunkA)
  float* core  = kn + 2 * M1;      // 2M
  float* Upre  = core + 2 * M1;    // 2M
  float* WpT   = Upre + 2 * M1;    // 2M
  float* Qdt   = WpT + 2 * M1;     // 2M
  float* Kdm   = Qdt + 2 * M1;     // 2M
  float* BqT   = Kdm + 2 * M1;     // 1M
  float* dec   = BqT + M1;         // 256
  float* ba    = dec + 256;        // 32768
  float* gb    = ba + 32768;       // 16384
  float* betab = gb + 16384;       // 16384
  float* rinfo = betab + 16384;    // 8192
  int*   ints  = (int*)(rinfo + 8192);
  int* cnt     = ints;             // 8
  int* cnt2    = ints + 8;         // 8
  int* offs    = ints + 16;        // 8
  int* pairTok = ints + 32;        // 4096
  int* tokPos  = ints + 4128;      // 4096
  u16* x1b     = (u16*)(ints + 8224);  // 2M u16

  u16* WgT = (u16*)conv;
  u16* WuT = (u16*)(conv + 2 * M1);
  u16* WdT = (u16*)kn;
  u16* act = (u16*)Kdm;             // after scan
  float* eo = Upre;                 // 4M f32 spans Upre+WpT (after scan)
  float* Schk0 = x1;                // 2M f32 (heads 0-3)
  float* Schk1 = qn;                // 2M f32 (heads 4-7)

  float* outF = (float*)d_out;
  const size_t N1 = (size_t)S * HID;

  hipMemsetAsync(cnt, 0, 16 * sizeof(int), stream);

  k_rms<<<S, 256, 0, stream>>>(hid, w_ln1, x1, x1b);
  k_sgemm2<<<dim3(24, 16), 256, 0, stream>>>(x1, W_qkvz, nullptr, qkvz, S, QKVZ_N, HID);
  k_ba<<<S, 256, 0, stream>>>(x1, W_ba, ba);
  k_bg<<<(S * HV + 255) / 256, 256, 0, stream>>>(ba, dt_bias, A_log, gb, betab);
  k_conv<<<(S * CONV_DIM) / 256, 256, 0, stream>>>(qkvz, conv_w, conv);
  k_prep<<<S, 512, 0, stream>>>(conv, qn, kn);
  k_chunkA<<<HV * NC, 256, 0, stream>>>(qn, kn, conv, gb, betab,
                                        Upre, WpT, Qdt, Kdm, BqT, dec);
  // conv/qn/kn dead -> MoE bf16 weights
  k_transp<<<dim3(16, 32, 8), 256, 0, stream>>>(W_gate, WgT, 1024, 512);
  k_transp<<<dim3(16, 32, 8), 256, 0, stream>>>(W_up, WuT, 1024, 512);
  k_transp<<<dim3(32, 16, 8), 256, 0, stream>>>(W_down, WdT, 512, 1024);
  k_chunkS<<<64, 256, 0, stream>>>(Upre, WpT, Kdm, dec, Schk0, Schk1);
  k_chunkO<<<dim3(8, 32, 8), 256, 0, stream>>>(Upre, WpT, Qdt, BqT, Schk0, Schk1, core);
  k_gatenorm<<<dim3(S, 2), 256, 0, stream>>>(core, qkvz, gnw, core);
  k_sgemm2<<<dim3(8, 16), 256, 0, stream>>>(core, W_out, hid, outF, S, HID, VAL_DIM);
  k_rms<<<S, 256, 0, stream>>>(outF, w_ln2, x1, x1b);
  k_router<<<S, 256, 0, stream>>>(x1, W_router, rinfo, cnt, outF + N1);
  k_offsets<<<1, 64, 0, stream>>>(cnt, offs, cnt2);
  k_scatter<<<(S + 255) / 256, 256, 0, stream>>>(rinfo, offs, cnt2, pairTok, tokPos);
  k_moe1m<<<dim3(4, 32, 8), 256, 0, stream>>>(x1b, WgT, WuT, offs, cnt, pairTok, act);
  k_moe2m<<<dim3(8, 32, 8), 256, 0, stream>>>(act, WdT, offs, cnt, eo);
  k_finish<<<S, 256, 0, stream>>>(eo, tokPos, rinfo, outF);
}